// Round 7
// baseline (5134.655 us; speedup 1.0000x reference)
//
#include <hip/hip_runtime.h>
#include <stdint.h>

#define TN 1024
#define CD 192
#define NB 8
#define NCLUST 196
#define NMERGE (TN - NCLUST)

typedef unsigned long long ull;

// Workgroup barrier WITHOUT global-memory drain (LDS made visible only).
#define LBAR() asm volatile("s_waitcnt lgkmcnt(0)\n\ts_barrier" ::: "memory")
// Full fence barrier: drains global stores too.
#define FBAR() asm volatile("s_waitcnt vmcnt(0) lgkmcnt(0)\n\ts_barrier" ::: "memory")

__device__ __forceinline__ uint32_t f2sort(float f) {
    uint32_t u = __float_as_uint(f);
    return u ^ ((u >> 31) ? 0xFFFFFFFFu : 0x80000000u);
}

template<int CTRL>
__device__ __forceinline__ ull dpp_min64(ull x) {
    int lo = (int)(uint32_t)x, hi = (int)(uint32_t)(x >> 32);
    int tlo = __builtin_amdgcn_update_dpp(lo, lo, CTRL, 0xF, 0xF, false);
    int thi = __builtin_amdgcn_update_dpp(hi, hi, CTRL, 0xF, 0xF, false);
    ull t = ((ull)(uint32_t)thi << 32) | (uint32_t)tlo;
    return (t < x) ? t : x;
}
__device__ __forceinline__ ull wmin64_all(ull x) {
    x = dpp_min64<0x111>(x); x = dpp_min64<0x112>(x);
    x = dpp_min64<0x114>(x); x = dpp_min64<0x118>(x);
    x = dpp_min64<0x142>(x); x = dpp_min64<0x143>(x);
    int lo = __builtin_amdgcn_readlane((int)(uint32_t)x, 63);
    int hi = __builtin_amdgcn_readlane((int)(uint32_t)(x >> 32), 63);
    return ((ull)(uint32_t)hi << 32) | (uint32_t)lo;
}

__device__ __forceinline__ ull shfl_min_ull(ull v) {   // init kernels only
    #pragma unroll
    for (int off = 32; off > 0; off >>= 1) {
        ull o = (ull)__shfl_xor((long long)v, off, 64);
        if (o < v) v = o;
    }
    return v;
}

// ---------------- normalize rows: xn = x / ||x|| ----------------
__global__ void norm_kernel(const float* __restrict__ x, float* __restrict__ xn) {
    int row = blockIdx.x;
    int t = threadIdx.x;
    __shared__ float ssum[4];
    float v = 0.f;
    if (t < CD) v = x[(size_t)row * CD + t];
    float s = v * v;
    #pragma unroll
    for (int off = 32; off > 0; off >>= 1) s += __shfl_xor(s, off, 64);
    if ((t & 63) == 0) ssum[t >> 6] = s;
    __syncthreads();
    float tot = ssum[0] + ssum[1] + ssum[2] + ssum[3];
    float nrm = __fsqrt_rn(tot);
    if (t < CD) xn[(size_t)row * CD + t] = __fdiv_rn(v, nrm);
}

// ---------------- dist = 1 - xn @ xn^T, 64x64 tiles ----------------
#define KC 32
__global__ __launch_bounds__(256) void dist_kernel(const float* __restrict__ xn,
                                                   float* __restrict__ dout,
                                                   float* __restrict__ dwork) {
    int b = blockIdx.z;
    int bm = blockIdx.y, bn = blockIdx.x;
    const float* X = xn + (size_t)b * TN * CD;
    __shared__ float As[KC][68];
    __shared__ float Bs[KC][68];
    int tid = threadIdx.x;
    int tx = tid & 15, ty = tid >> 4;
    int lr = tid >> 2;
    int lq = tid & 3;
    float acc[4][4];
    #pragma unroll
    for (int r = 0; r < 4; ++r)
        #pragma unroll
        for (int c = 0; c < 4; ++c) acc[r][c] = 0.f;

    for (int kc = 0; kc < CD; kc += KC) {
        float4 a0 = *(const float4*)&X[(size_t)(bm * 64 + lr) * CD + kc + lq * 4];
        float4 a1 = *(const float4*)&X[(size_t)(bm * 64 + lr) * CD + kc + (lq + 4) * 4];
        float4 b0 = *(const float4*)&X[(size_t)(bn * 64 + lr) * CD + kc + lq * 4];
        float4 b1 = *(const float4*)&X[(size_t)(bn * 64 + lr) * CD + kc + (lq + 4) * 4];
        __syncthreads();
        As[lq * 4 + 0][lr] = a0.x; As[lq * 4 + 1][lr] = a0.y;
        As[lq * 4 + 2][lr] = a0.z; As[lq * 4 + 3][lr] = a0.w;
        As[lq * 4 + 16][lr] = a1.x; As[lq * 4 + 17][lr] = a1.y;
        As[lq * 4 + 18][lr] = a1.z; As[lq * 4 + 19][lr] = a1.w;
        Bs[lq * 4 + 0][lr] = b0.x; Bs[lq * 4 + 1][lr] = b0.y;
        Bs[lq * 4 + 2][lr] = b0.z; Bs[lq * 4 + 3][lr] = b0.w;
        Bs[lq * 4 + 16][lr] = b1.x; Bs[lq * 4 + 17][lr] = b1.y;
        Bs[lq * 4 + 18][lr] = b1.z; Bs[lq * 4 + 19][lr] = b1.w;
        __syncthreads();
        #pragma unroll
        for (int kk = 0; kk < KC; ++kk) {
            float4 av = *(const float4*)&As[kk][ty * 4];
            float4 bv = *(const float4*)&Bs[kk][tx * 4];
            acc[0][0] += av.x * bv.x; acc[0][1] += av.x * bv.y;
            acc[0][2] += av.x * bv.z; acc[0][3] += av.x * bv.w;
            acc[1][0] += av.y * bv.x; acc[1][1] += av.y * bv.y;
            acc[1][2] += av.y * bv.z; acc[1][3] += av.y * bv.w;
            acc[2][0] += av.z * bv.x; acc[2][1] += av.z * bv.y;
            acc[2][2] += av.z * bv.z; acc[2][3] += av.z * bv.w;
            acc[3][0] += av.w * bv.x; acc[3][1] += av.w * bv.y;
            acc[3][2] += av.w * bv.z; acc[3][3] += av.w * bv.w;
        }
    }
    size_t obase = (size_t)b * TN * TN;
    #pragma unroll
    for (int r = 0; r < 4; ++r) {
        int mrow = bm * 64 + ty * 4 + r;
        float4 o;
        o.x = 1.0f - acc[r][0]; o.y = 1.0f - acc[r][1];
        o.z = 1.0f - acc[r][2]; o.w = 1.0f - acc[r][3];
        size_t idx = obase + (size_t)mrow * TN + bn * 64 + tx * 4;
        *(float4*)&dout[idx] = o;
        *(float4*)&dwork[idx] = o;
    }
}

// ---------------- per-row top-2 init ----------------
__global__ void rowmin_init_kernel(const float* __restrict__ D,
                                   ull* __restrict__ rowkey, ull* __restrict__ rowkey2) {
    int gid = blockIdx.x;
    int bb = gid >> 10, r = gid & 1023;
    const float* Drow = D + (size_t)bb * TN * TN + (size_t)r * TN;
    int t = threadIdx.x;
    __shared__ ull part[4];
    __shared__ ull m1s;
    ull k = ~0ull;
    for (int s = t; s < TN; s += 256) {
        if (s != r) {
            ull key = ((ull)f2sort(Drow[s]) << 32) | (uint32_t)s;
            if (key < k) k = key;
        }
    }
    k = shfl_min_ull(k);
    if ((t & 63) == 0) part[t >> 6] = k;
    __syncthreads();
    if (t == 0) {
        ull m = part[0];
        #pragma unroll
        for (int w = 1; w < 4; ++w) if (part[w] < m) m = part[w];
        rowkey[gid] = m;
        m1s = m;
    }
    __syncthreads();
    ull m1 = m1s;
    int c1 = (int)(uint32_t)m1;
    ull k2 = ~0ull;
    for (int s = t; s < TN; s += 256) {
        if (s != r && s != c1) {
            ull key = ((ull)f2sort(Drow[s]) << 32) | (uint32_t)s;
            if (key < k2) k2 = key;
        }
    }
    k2 = shfl_min_ull(k2);
    __syncthreads();
    if ((t & 63) == 0) part[t >> 6] = k2;
    __syncthreads();
    if (t == 0) {
        ull m = part[0];
        #pragma unroll
        for (int w = 1; w < 4; ++w) if (part[w] < m) m = part[w];
        rowkey2[gid] = m;
    }
}

// ---------------- clustering: 8 waves = 4 compute + 4 writer ----------------
// 2 barriers/iter. Compute waves issue NO scattered stores (vmcnt clean);
// writer waves replay row/col stores from the LDS journal during region C.
// Phase A scan for iter m+1 runs concurrently with Phase C rescans of iter m;
// rescanned rows are poisoned and their fresh keys routed through rm[] atomicMin.
__global__ __launch_bounds__(512) void cluster_kernel(float* __restrict__ D,
                                                      const ull* __restrict__ rk_init,
                                                      const ull* __restrict__ rk2_init,
                                                      float* __restrict__ out_labels) {
    int b = blockIdx.x;
    float* Db = D + (size_t)b * TN * TN;
    int k = threadIdx.x;               // 0..511
    int lane = k & 63, wave = k >> 6;  // waves 0-3 compute, 4-7 writer
    int s0 = (k & 255) * 4;            // element base (compute / writer each cover 0..1023)

    __shared__ float Jl[16 * TN];      // 64 KB journal ring
    __shared__ ull rowkey[TN];         // min1 key: (val<<32)|col ; ~0 = dead/pending
    __shared__ ull rowkey2[TN];        // min2 key or ~0 = unknown
    __shared__ float sizes_l[TN];
    __shared__ int ts_l[TN] __attribute__((aligned(16)));
    __shared__ int parent_l[TN];
    __shared__ uint32_t aw[TN / 32];
    __shared__ int list_l[TN];
    __shared__ int nrecb[2];
    __shared__ ull rm[2];              // rescan/row-i argmin contributions (val<<32)|row
    __shared__ ull wpA[4], wpB1[4], wpB2[4];
    __shared__ int bc_i;
    __shared__ int wtarg[8];
    __shared__ int woff[32];

    #pragma unroll
    for (int t = 0; t < 2; ++t) {
        int idx = k + 512 * t;
        rowkey[idx] = rk_init[b * TN + idx];
        rowkey2[idx] = rk2_init[b * TN + idx];
        sizes_l[idx] = 1.0f;
        ts_l[idx] = -1000000;
        parent_l[idx] = idx;
    }
    if (k < 32) aw[k] = 0xFFFFFFFFu;
    if (k < 2) { nrecb[k] = 0; rm[k] = ~0ull; }
    __syncthreads();

    // prologue: A-scan for m=0 (compute waves)
    if (wave < 4) {
        ull best = ~0ull;
        #pragma unroll
        for (int e = 0; e < 4; ++e) {
            int s = s0 + e;
            ull cand = (rowkey[s] & 0xFFFFFFFF00000000ull) | (uint32_t)s;
            if (cand < best) best = cand;
        }
        best = wmin64_all(best);
        if (lane == 0) wpA[wave] = best;
    }
    __syncthreads();

    for (int m = 0; m < NMERGE; ++m) {
        int m16 = m - 16;
        int i = 0, j = 0;
        float ssum = 0.f;

        // =================== region 2: select + merge + maintain ===================
        if (wave < 4) {
            ull g = wpA[0];
            { ull t1 = wpA[1]; if (t1 < g) g = t1;
              ull t2 = wpA[2]; if (t2 < g) g = t2;
              ull t3 = wpA[3]; if (t3 < g) g = t3;
              ull t4 = rm[m & 1]; if (t4 < g) g = t4; }
            i = (int)(uint32_t)g;
            j = (int)(uint32_t)rowkey[i];
            float ni = sizes_l[i], nj = sizes_l[j];
            int tsi = ts_l[i], tsj = ts_l[j];
            ssum = __fadd_rn(ni, nj);

            ull K0[4], M0[4];
            #pragma unroll
            for (int e = 0; e < 4; ++e) { K0[e] = rowkey[s0 + e]; M0[e] = rowkey2[s0 + e]; }
            int4 ts4 = *(const int4*)&ts_l[s0];

            // Phase B: fresh rows i,j (uniform journal fast path)
            float di[4], dj[4];
            if (tsi > m16) {
                #pragma unroll
                for (int e = 0; e < 4; ++e) {
                    int tss = (&ts4.x)[e];
                    di[e] = (tss > tsi) ? Jl[(tss & 15) * TN + i] : Jl[(tsi & 15) * TN + (s0 + e)];
                }
            } else {
                float4 gv = *(const float4*)(Db + (size_t)i * TN + s0);
                #pragma unroll
                for (int e = 0; e < 4; ++e) {
                    int tss = (&ts4.x)[e];
                    di[e] = (tss > m16) ? Jl[(tss & 15) * TN + i] : (&gv.x)[e];
                }
            }
            if (tsj > m16) {
                #pragma unroll
                for (int e = 0; e < 4; ++e) {
                    int tss = (&ts4.x)[e];
                    dj[e] = (tss > tsj) ? Jl[(tss & 15) * TN + j] : Jl[(tsj & 15) * TN + (s0 + e)];
                }
            } else {
                float4 gv = *(const float4*)(Db + (size_t)j * TN + s0);
                #pragma unroll
                for (int e = 0; e < 4; ++e) {
                    int tss = (&ts4.x)[e];
                    dj[e] = (tss > m16) ? Jl[(tss & 15) * TN + j] : (&gv.x)[e];
                }
            }
            float4 nr4;
            #pragma unroll
            for (int e = 0; e < 4; ++e)
                (&nr4.x)[e] = __fdiv_rn(__fadd_rn(__fmul_rn(ni, di[e]), __fmul_rn(nj, dj[e])), ssum);
            *(float4*)&Jl[(m & 15) * TN + s0] = nr4;      // journal only; global via writers

            // fused row-i top-2 (per-thread u64 keys, then wave top-2)
            ull a1 = ~0ull, a2 = ~0ull;
            #pragma unroll
            for (int e = 0; e < 4; ++e) {
                int s = s0 + e;
                if (K0[e] != ~0ull && s != i && s != j) {
                    ull key = ((ull)f2sort((&nr4.x)[e]) << 32) | (uint32_t)s;
                    if (key < a1) { a2 = a1; a1 = key; }
                    else if (key < a2) a2 = key;
                }
            }
            ull m1 = wmin64_all(a1);
            ull bm = __ballot(a1 == m1);
            int lw = __ffsll((long long)bm) - 1;
            ull aa = (lane == lw) ? a2 : a1;
            ull m2 = wmin64_all(aa);
            if (lane == 0) { wpB1[wave] = m1; wpB2[wave] = m2; }

            // Phase D: top-2 incremental maintenance
            #pragma unroll
            for (int e = 0; e < 4; ++e) {
                int s = s0 + e;
                ull K = K0[e];
                if (K == ~0ull || s == i || s == j) continue;
                ull M = M0[e];
                ull nk = ((ull)f2sort((&nr4.x)[e]) << 32) | (uint32_t)i;
                uint32_t c1 = (uint32_t)K;
                bool k1 = (c1 == (uint32_t)i) || (c1 == (uint32_t)j);
                bool mvalid = (M != ~0ull);
                if (mvalid) {
                    uint32_t c2 = (uint32_t)M;
                    if (c2 == (uint32_t)i || c2 == (uint32_t)j) mvalid = false;
                }
                if (!k1) {
                    if (nk < K) { rowkey[s] = nk; rowkey2[s] = K; }
                    else rowkey2[s] = mvalid ? ((nk < M) ? nk : M) : ~0ull;
                } else {
                    if (mvalid) {
                        if (nk < M) { rowkey[s] = nk; rowkey2[s] = M; }
                        else { rowkey[s] = M; rowkey2[s] = ~0ull; }
                    } else {
                        rowkey[s] = ~0ull; rowkey2[s] = ~0ull;   // poison for concurrent A-scan
                        int idx = atomicAdd(&nrecb[m & 1], 1); list_l[idx] = s;
                    }
                }
            }
            // owner-of-j bookkeeping
            if ((j >> 2) == k) {
                rowkey[j] = ~0ull; rowkey2[j] = ~0ull;
                parent_l[j] = i;
                aw[j >> 5] &= ~(1u << (j & 31));
            }
            if (k == 0) { nrecb[(m & 1) ^ 1] = 0; bc_i = i; }
        }
        LBAR();                                            // barX

        // =================== region 1: C (rescans) ∥ A-scan(m+1) ∥ writer stores ===================
        if (wave < 4) {
            if (k == 0) {
                rm[m & 1] = ~0ull;                         // consumed at final-min(m)
                // finalize row i's top-2 from the 4 wave partials
                ull m1 = ~0ull, m2 = ~0ull;
                #pragma unroll
                for (int w = 0; w < 4; ++w) {
                    ull a = wpB1[w], b2 = wpB2[w];
                    if (a < m1) { m2 = (m1 < b2) ? m1 : b2; m1 = a; }
                    else { if (a < m2) m2 = a; }
                }
                rowkey[i] = m1; rowkey2[i] = m2;
                atomicMin(&rm[(m + 1) & 1], (m1 & 0xFFFFFFFF00000000ull) | (uint32_t)i);
            }
            if ((i >> 2) == k) { ts_l[i] = m; sizes_l[i] = ssum; wtarg[m & 7] = i; }

            // A-scan for m+1 (skip i explicitly; j & pending rows are poisoned)
            {
                ull best = ~0ull;
                #pragma unroll
                for (int e = 0; e < 4; ++e) {
                    int s = s0 + e;
                    if (s == i) continue;
                    ull cand = (rowkey[s] & 0xFFFFFFFF00000000ull) | (uint32_t)s;
                    if (cand < best) best = cand;
                }
                best = wmin64_all(best);
                if (lane == 0) wpA[wave] = best;
            }

            // rescans (exact top-2 rebuild)
            int ncr = nrecb[m & 1];
            for (int z = wave; z < ncr; z += 4) {
                int r = list_l[z];
                int tsr = ts_l[r];
                const float* Rr = Db + (size_t)r * TN;
                ull a1 = ~0ull, a2 = ~0ull;
                #pragma unroll
                for (int q = 0; q < 4; ++q) {
                    int sq = (lane << 2) + (q << 8);
                    float4 v = *(const float4*)(Rr + sq);
                    int4 t4 = *(const int4*)&ts_l[sq];
                    uint32_t bits = (aw[sq >> 5] >> (sq & 31)) & 0xFu;
                    #pragma unroll
                    for (int e = 0; e < 4; ++e) {
                        int s = sq + e;
                        if (!((bits >> e) & 1u) || s == r) continue;
                        float val;
                        if (s == i) val = Jl[(m & 15) * TN + r];
                        else {
                            int tss = (&t4.x)[e];
                            int tm = (tss > tsr) ? tss : tsr;
                            val = (tm > m16) ? ((tss > tsr) ? Jl[(tss & 15) * TN + r]
                                                            : Jl[(tsr & 15) * TN + s])
                                             : (&v.x)[e];
                        }
                        ull key = ((ull)f2sort(val) << 32) | (uint32_t)s;
                        if (key < a1) { a2 = a1; a1 = key; }
                        else if (key < a2) a2 = key;
                    }
                }
                ull m1 = wmin64_all(a1);
                ull bm = __ballot(a1 == m1);
                int lw = __ffsll((long long)bm) - 1;
                ull aa = (lane == lw) ? a2 : a1;
                ull m2 = wmin64_all(aa);
                if (lane == 0) {
                    rowkey[r] = m1; rowkey2[r] = m2;
                    atomicMin(&rm[(m + 1) & 1], (m1 & 0xFFFFFFFF00000000ull) | (uint32_t)r);
                }
            }
        } else {
            // writer waves: replay row + column stores from the journal
            int i2 = bc_i;
            float4 nrw = *(const float4*)&Jl[(m & 15) * TN + s0];
            *(float4*)(Db + (size_t)i2 * TN + s0) = nrw;            // coalesced row
            uint32_t bits = (aw[s0 >> 5] >> (s0 & 31)) & 0xFu;
            #pragma unroll
            for (int e = 0; e < 4; ++e)
                if ((bits >> e) & 1u)
                    Db[(size_t)(s0 + e) * TN + i2] = (&nrw.x)[e];   // scattered col
        }

        // barY: light barrier; every 8th iter full fence + race fix-up
        if ((m & 7) == 7) {
            FBAR();
            if (k < 64) {
                int t1 = k >> 3, t2 = k & 7;
                if (t1 != t2) {
                    int a = wtarg[t1], c = wtarg[t2];
                    if (a != c) {
                        bool lastA = true, lastC = true;
                        #pragma unroll
                        for (int t = 0; t < 8; ++t) {
                            if (t > t1 && wtarg[t] == a) lastA = false;
                            if (t > t2 && wtarg[t] == c) lastC = false;
                        }
                        if (lastA && lastC) {
                            int later = (t1 > t2) ? t1 : t2;
                            int earlier_i = (t1 > t2) ? c : a;
                            int iterlater = (m & ~7) + later;
                            float v = Jl[(iterlater & 15) * TN + earlier_i];
                            Db[(size_t)a * TN + c] = v;
                        }
                    }
                }
            }
            FBAR();
        } else {
            LBAR();
        }
    }

    // ---- epilogue: labels = rank of cluster root among active reps ----
    __syncthreads();
    if (k == 0) {
        int run = 0;
        for (int w = 0; w < 32; ++w) { woff[w] = run; run += __popc(aw[w]); }
    }
    __syncthreads();
    #pragma unroll
    for (int t = 0; t < 2; ++t) {
        int idx = k + 512 * t;
        int p = idx;
        while (!((aw[p >> 5] >> (p & 31)) & 1u)) p = parent_l[p];
        int rank = woff[p >> 5] + __popc(aw[p >> 5] & ((1u << (p & 31)) - 1u));
        out_labels[(size_t)b * TN + idx] = (float)rank;
    }
}

extern "C" void kernel_launch(void* const* d_in, const int* in_sizes, int n_in,
                              void* d_out, int out_size, void* d_ws, size_t ws_size,
                              hipStream_t stream) {
    const float* x = (const float*)d_in[0];
    float* out = (float*)d_out;

    float* xn      = (float*)d_ws;                          // NB*TN*CD floats
    float* Dwork   = xn + (size_t)NB * TN * CD;             // NB*TN*TN floats
    ull*   rowkey  = (ull*)(Dwork + (size_t)NB * TN * TN);  // NB*TN u64
    ull*   rowkey2 = rowkey + (size_t)NB * TN;              // NB*TN u64

    float* dist_out   = out;
    float* labels_out = out + (size_t)NB * TN * TN;

    norm_kernel<<<NB * TN, 256, 0, stream>>>(x, xn);
    dim3 g2(16, 16, NB);
    dist_kernel<<<g2, 256, 0, stream>>>(xn, dist_out, Dwork);
    rowmin_init_kernel<<<NB * TN, 256, 0, stream>>>(Dwork, rowkey, rowkey2);
    cluster_kernel<<<NB, 512, 0, stream>>>(Dwork, rowkey, rowkey2, labels_out);
}

// Round 8
// 5037.821 us; speedup vs baseline: 1.0192x; 1.0192x over previous
//
#include <hip/hip_runtime.h>
#include <stdint.h>

#define TN 1024
#define CD 192
#define NB 8
#define NCLUST 196
#define NMERGE (TN - NCLUST)
#define HIMASK 0xFFFFFFFF00000000ull

typedef unsigned long long ull;

// Workgroup barrier WITHOUT global-memory drain (LDS made visible only).
#define LBAR() asm volatile("s_waitcnt lgkmcnt(0)\n\ts_barrier" ::: "memory")
// Full fence barrier: drains global stores too.
#define FBAR() asm volatile("s_waitcnt vmcnt(0) lgkmcnt(0)\n\ts_barrier" ::: "memory")

__device__ __forceinline__ uint32_t f2sort(float f) {
    uint32_t u = __float_as_uint(f);
    return u ^ ((u >> 31) ? 0xFFFFFFFFu : 0x80000000u);
}

template<int CTRL>
__device__ __forceinline__ ull dpp_min64(ull x) {
    int lo = (int)(uint32_t)x, hi = (int)(uint32_t)(x >> 32);
    int tlo = __builtin_amdgcn_update_dpp(lo, lo, CTRL, 0xF, 0xF, false);
    int thi = __builtin_amdgcn_update_dpp(hi, hi, CTRL, 0xF, 0xF, false);
    ull t = ((ull)(uint32_t)thi << 32) | (uint32_t)tlo;
    return (t < x) ? t : x;
}
__device__ __forceinline__ ull wmin64_all(ull x) {
    x = dpp_min64<0x111>(x); x = dpp_min64<0x112>(x);
    x = dpp_min64<0x114>(x); x = dpp_min64<0x118>(x);
    x = dpp_min64<0x142>(x); x = dpp_min64<0x143>(x);
    int lo = __builtin_amdgcn_readlane((int)(uint32_t)x, 63);
    int hi = __builtin_amdgcn_readlane((int)(uint32_t)(x >> 32), 63);
    return ((ull)(uint32_t)hi << 32) | (uint32_t)lo;
}
// min over lanes 0..15 (lanes 16+ must hold ~0), broadcast
__device__ __forceinline__ ull wmin64_16(ull x) {
    x = dpp_min64<0x111>(x); x = dpp_min64<0x112>(x);
    x = dpp_min64<0x114>(x); x = dpp_min64<0x118>(x);
    int lo = __builtin_amdgcn_readlane((int)(uint32_t)x, 15);
    int hi = __builtin_amdgcn_readlane((int)(uint32_t)(x >> 32), 15);
    return ((ull)(uint32_t)hi << 32) | (uint32_t)lo;
}

__device__ __forceinline__ ull shfl_min_ull(ull v) {   // init kernels only
    #pragma unroll
    for (int off = 32; off > 0; off >>= 1) {
        ull o = (ull)__shfl_xor((long long)v, off, 64);
        if (o < v) v = o;
    }
    return v;
}

// ---------------- normalize rows: xn = x / ||x|| ----------------
__global__ void norm_kernel(const float* __restrict__ x, float* __restrict__ xn) {
    int row = blockIdx.x;
    int t = threadIdx.x;
    __shared__ float ssum[4];
    float v = 0.f;
    if (t < CD) v = x[(size_t)row * CD + t];
    float s = v * v;
    #pragma unroll
    for (int off = 32; off > 0; off >>= 1) s += __shfl_xor(s, off, 64);
    if ((t & 63) == 0) ssum[t >> 6] = s;
    __syncthreads();
    float tot = ssum[0] + ssum[1] + ssum[2] + ssum[3];
    float nrm = __fsqrt_rn(tot);
    if (t < CD) xn[(size_t)row * CD + t] = __fdiv_rn(v, nrm);
}

// ---------------- dist = 1 - xn @ xn^T, 64x64 tiles ----------------
#define KC 32
__global__ __launch_bounds__(256) void dist_kernel(const float* __restrict__ xn,
                                                   float* __restrict__ dout,
                                                   float* __restrict__ dwork) {
    int b = blockIdx.z;
    int bm = blockIdx.y, bn = blockIdx.x;
    const float* X = xn + (size_t)b * TN * CD;
    __shared__ float As[KC][68];
    __shared__ float Bs[KC][68];
    int tid = threadIdx.x;
    int tx = tid & 15, ty = tid >> 4;
    int lr = tid >> 2;
    int lq = tid & 3;
    float acc[4][4];
    #pragma unroll
    for (int r = 0; r < 4; ++r)
        #pragma unroll
        for (int c = 0; c < 4; ++c) acc[r][c] = 0.f;

    for (int kc = 0; kc < CD; kc += KC) {
        float4 a0 = *(const float4*)&X[(size_t)(bm * 64 + lr) * CD + kc + lq * 4];
        float4 a1 = *(const float4*)&X[(size_t)(bm * 64 + lr) * CD + kc + (lq + 4) * 4];
        float4 b0 = *(const float4*)&X[(size_t)(bn * 64 + lr) * CD + kc + lq * 4];
        float4 b1 = *(const float4*)&X[(size_t)(bn * 64 + lr) * CD + kc + (lq + 4) * 4];
        __syncthreads();
        As[lq * 4 + 0][lr] = a0.x; As[lq * 4 + 1][lr] = a0.y;
        As[lq * 4 + 2][lr] = a0.z; As[lq * 4 + 3][lr] = a0.w;
        As[lq * 4 + 16][lr] = a1.x; As[lq * 4 + 17][lr] = a1.y;
        As[lq * 4 + 18][lr] = a1.z; As[lq * 4 + 19][lr] = a1.w;
        Bs[lq * 4 + 0][lr] = b0.x; Bs[lq * 4 + 1][lr] = b0.y;
        Bs[lq * 4 + 2][lr] = b0.z; Bs[lq * 4 + 3][lr] = b0.w;
        Bs[lq * 4 + 16][lr] = b1.x; Bs[lq * 4 + 17][lr] = b1.y;
        Bs[lq * 4 + 18][lr] = b1.z; Bs[lq * 4 + 19][lr] = b1.w;
        __syncthreads();
        #pragma unroll
        for (int kk = 0; kk < KC; ++kk) {
            float4 av = *(const float4*)&As[kk][ty * 4];
            float4 bv = *(const float4*)&Bs[kk][tx * 4];
            acc[0][0] += av.x * bv.x; acc[0][1] += av.x * bv.y;
            acc[0][2] += av.x * bv.z; acc[0][3] += av.x * bv.w;
            acc[1][0] += av.y * bv.x; acc[1][1] += av.y * bv.y;
            acc[1][2] += av.y * bv.z; acc[1][3] += av.y * bv.w;
            acc[2][0] += av.z * bv.x; acc[2][1] += av.z * bv.y;
            acc[2][2] += av.z * bv.z; acc[2][3] += av.z * bv.w;
            acc[3][0] += av.w * bv.x; acc[3][1] += av.w * bv.y;
            acc[3][2] += av.w * bv.z; acc[3][3] += av.w * bv.w;
        }
    }
    size_t obase = (size_t)b * TN * TN;
    #pragma unroll
    for (int r = 0; r < 4; ++r) {
        int mrow = bm * 64 + ty * 4 + r;
        float4 o;
        o.x = 1.0f - acc[r][0]; o.y = 1.0f - acc[r][1];
        o.z = 1.0f - acc[r][2]; o.w = 1.0f - acc[r][3];
        size_t idx = obase + (size_t)mrow * TN + bn * 64 + tx * 4;
        *(float4*)&dout[idx] = o;
        *(float4*)&dwork[idx] = o;
    }
}

// ---------------- per-row top-2 init ----------------
__global__ void rowmin_init_kernel(const float* __restrict__ D,
                                   ull* __restrict__ rowkey, ull* __restrict__ rowkey2) {
    int gid = blockIdx.x;
    int bb = gid >> 10, r = gid & 1023;
    const float* Drow = D + (size_t)bb * TN * TN + (size_t)r * TN;
    int t = threadIdx.x;
    __shared__ ull part[4];
    __shared__ ull m1s;
    ull k = ~0ull;
    for (int s = t; s < TN; s += 256) {
        if (s != r) {
            ull key = ((ull)f2sort(Drow[s]) << 32) | (uint32_t)s;
            if (key < k) k = key;
        }
    }
    k = shfl_min_ull(k);
    if ((t & 63) == 0) part[t >> 6] = k;
    __syncthreads();
    if (t == 0) {
        ull m = part[0];
        #pragma unroll
        for (int w = 1; w < 4; ++w) if (part[w] < m) m = part[w];
        rowkey[gid] = m;
        m1s = m;
    }
    __syncthreads();
    ull m1 = m1s;
    int c1 = (int)(uint32_t)m1;
    ull k2 = ~0ull;
    for (int s = t; s < TN; s += 256) {
        if (s != r && s != c1) {
            ull key = ((ull)f2sort(Drow[s]) << 32) | (uint32_t)s;
            if (key < k2) k2 = key;
        }
    }
    k2 = shfl_min_ull(k2);
    __syncthreads();
    if ((t & 63) == 0) part[t >> 6] = k2;
    __syncthreads();
    if (t == 0) {
        ull m = part[0];
        #pragma unroll
        for (int w = 1; w < 4; ++w) if (part[w] < m) m = part[w];
        rowkey2[gid] = m;
    }
}

// ---------------- clustering: 8 waves, 2 barriers/iter, fused A-scan ----------------
// Thread k owns elements {k, k+512} (stride-1 LDS patterns). Region X: final-min
// (redundant, from wpA[8]+rm), Phase B (journal bridge), fused row-i top-2 partials,
// Phase D top-2 maintenance, A-partials for m+1 from post-D registers. Region Y:
// wave0 finalizes row-i top-2 (-> rm), waves 1-7 rescan invalidated rows (-> rm),
// owner threads apply deferred state updates. Journal/FBAR/fixup as R5/R6.
__global__ __launch_bounds__(512) void cluster_kernel(float* __restrict__ D,
                                                      const ull* __restrict__ rk_init,
                                                      const ull* __restrict__ rk2_init,
                                                      float* __restrict__ out_labels) {
    int b = blockIdx.x;
    float* Db = D + (size_t)b * TN * TN;
    int k = threadIdx.x;               // 0..511
    int lane = k & 63, wave = k >> 6;  // 8 waves
    int e0 = k, e1 = k + 512;

    __shared__ float Jl[16 * TN];      // 64 KB journal ring
    __shared__ ull rowkey[TN];         // min1 key: (val<<32)|col ; ~0 = dead/pending
    __shared__ ull rowkey2[TN];        // min2 key or ~0 = unknown
    __shared__ float sizes_l[TN];
    __shared__ int ts_l[TN];
    __shared__ int parent_l[TN];
    __shared__ uint32_t aw[TN / 32];
    __shared__ int list_l[TN];
    __shared__ int nrecb[2];
    __shared__ ull rm[2];              // fresh keys of row-i / rescanned rows
    __shared__ ull wpA[8], wpB1[8], wpB2[8];
    __shared__ int wtarg[8];
    __shared__ int woff[32];

    rowkey[e0] = rk_init[b * TN + e0];   rowkey[e1] = rk_init[b * TN + e1];
    rowkey2[e0] = rk2_init[b * TN + e0]; rowkey2[e1] = rk2_init[b * TN + e1];
    sizes_l[e0] = 1.0f; sizes_l[e1] = 1.0f;
    ts_l[e0] = -1000000; ts_l[e1] = -1000000;
    parent_l[e0] = e0;  parent_l[e1] = e1;
    if (k < 32) aw[k] = 0xFFFFFFFFu;
    if (k < 2) { nrecb[k] = 0; rm[k] = ~0ull; }
    __syncthreads();

    // prologue: A-partials for m=0
    {
        ull c0 = (rowkey[e0] & HIMASK) | (uint32_t)e0;
        ull c1 = (rowkey[e1] & HIMASK) | (uint32_t)e1;
        ull best = (c0 < c1) ? c0 : c1;
        best = wmin64_all(best);
        if (lane == 0) wpA[wave] = best;
    }
    __syncthreads();

    for (int m = 0; m < NMERGE; ++m) {
        int m16 = m - 16;
        int slot = m & 15;

        // =================== region X ===================
        // final-min (redundant in every wave)
        ull v = (lane < 8) ? wpA[lane] : ((lane == 8) ? rm[m & 1] : ~0ull);
        ull g = wmin64_16(v);
        int i = (int)(uint32_t)g;
        int j = (int)(uint32_t)rowkey[i];
        float ni = sizes_l[i], nj = sizes_l[j];
        int tsi = ts_l[i], tsj = ts_l[j];
        float ssum = __fadd_rn(ni, nj);

        ull K0a = rowkey[e0], K0b = rowkey[e1];
        ull M0a = rowkey2[e0], M0b = rowkey2[e1];
        int tsa = ts_l[e0], tsb = ts_l[e1];

        // Phase B: fresh rows i,j (uniform journal fast path), merged values
        float dia, dib, dja, djb;
        if (tsi > m16) {
            dia = (tsa > tsi) ? Jl[(tsa & 15) * TN + i] : Jl[(tsi & 15) * TN + e0];
            dib = (tsb > tsi) ? Jl[(tsb & 15) * TN + i] : Jl[(tsi & 15) * TN + e1];
        } else {
            float g0 = Db[(size_t)i * TN + e0];
            float g1 = Db[(size_t)i * TN + e1];
            dia = (tsa > m16) ? Jl[(tsa & 15) * TN + i] : g0;
            dib = (tsb > m16) ? Jl[(tsb & 15) * TN + i] : g1;
        }
        if (tsj > m16) {
            dja = (tsa > tsj) ? Jl[(tsa & 15) * TN + j] : Jl[(tsj & 15) * TN + e0];
            djb = (tsb > tsj) ? Jl[(tsb & 15) * TN + j] : Jl[(tsj & 15) * TN + e1];
        } else {
            float g0 = Db[(size_t)j * TN + e0];
            float g1 = Db[(size_t)j * TN + e1];
            dja = (tsa > m16) ? Jl[(tsa & 15) * TN + j] : g0;
            djb = (tsb > m16) ? Jl[(tsb & 15) * TN + j] : g1;
        }
        float nra = __fdiv_rn(__fadd_rn(__fmul_rn(ni, dia), __fmul_rn(nj, dja)), ssum);
        float nrb = __fdiv_rn(__fadd_rn(__fmul_rn(ni, dib), __fmul_rn(nj, djb)), ssum);
        Jl[slot * TN + e0] = nra;
        Jl[slot * TN + e1] = nrb;

        // fused row-i top-2 partials
        ull a1 = ~0ull, a2 = ~0ull;
        if (K0a != ~0ull && e0 != i && e0 != j) {
            a1 = ((ull)f2sort(nra) << 32) | (uint32_t)e0;
        }
        if (K0b != ~0ull && e1 != i && e1 != j) {
            ull key = ((ull)f2sort(nrb) << 32) | (uint32_t)e1;
            if (key < a1) { a2 = a1; a1 = key; } else a2 = key;
        }
        {
            ull m1 = wmin64_all(a1);
            ull bm = __ballot(a1 == m1);
            int lw = __ffsll((long long)bm) - 1;
            ull aa = (lane == lw) ? a2 : a1;
            ull m2 = wmin64_all(aa);
            if (lane == 0) { wpB1[wave] = m1; wpB2[wave] = m2; }
        }

        // Phase D: top-2 incremental maintenance (returns post-D key or ~0)
        auto phaseD = [&](int s, ull K, ull M, float nrv) -> ull {
            if (K == ~0ull || s == i || s == j) {
                if (s == j) {                       // owner poisons j
                    rowkey[s] = ~0ull; rowkey2[s] = ~0ull;
                    parent_l[s] = i;
                    aw[s >> 5] &= ~(1u << (s & 31));
                }
                return ~0ull;
            }
            ull nk = ((ull)f2sort(nrv) << 32) | (uint32_t)i;
            uint32_t c1 = (uint32_t)K;
            bool k1 = (c1 == (uint32_t)i) || (c1 == (uint32_t)j);
            bool mvalid = (M != ~0ull);
            if (mvalid) {
                uint32_t c2 = (uint32_t)M;
                if (c2 == (uint32_t)i || c2 == (uint32_t)j) mvalid = false;
            }
            if (!k1) {
                if (nk < K) { rowkey[s] = nk; rowkey2[s] = K; return nk; }
                rowkey2[s] = mvalid ? ((nk < M) ? nk : M) : ~0ull;
                return K;
            } else {
                if (mvalid) {
                    if (nk < M) { rowkey[s] = nk; rowkey2[s] = M; return nk; }
                    rowkey[s] = M; rowkey2[s] = ~0ull; return M;
                }
                rowkey[s] = ~0ull; rowkey2[s] = ~0ull;       // pending rescan
                int idx = atomicAdd(&nrecb[m & 1], 1); list_l[idx] = s;
                return ~0ull;
            }
        };
        ull nKa = phaseD(e0, K0a, M0a, nra);
        ull nKb = phaseD(e1, K0b, M0b, nrb);

        // A-partials for merge m+1 (from post-D registers)
        {
            ull c0 = (nKa != ~0ull) ? ((nKa & HIMASK) | (uint32_t)e0) : ~0ull;
            ull c1 = (nKb != ~0ull) ? ((nKb & HIMASK) | (uint32_t)e1) : ~0ull;
            ull best = (c0 < c1) ? c0 : c1;
            best = wmin64_all(best);
            if (lane == 0) wpA[wave] = best;
        }
        if (k == 0) nrecb[(m & 1) ^ 1] = 0;

        // global stores last: coalesced row i + fire-and-forget scattered col i
        Db[(size_t)i * TN + e0] = nra;
        Db[(size_t)i * TN + e1] = nrb;
        if (K0a != ~0ull) Db[(size_t)e0 * TN + i] = nra;
        if (K0b != ~0ull) Db[(size_t)e1 * TN + i] = nrb;

        LBAR();                                              // bar1

        // =================== region Y ===================
        int ncr = nrecb[m & 1];
        if (wave == 0) {
            // finalize row i's top-2 from the 8 wave partials
            ull a = (lane < 8) ? wpB1[lane] : ~0ull;
            ull bb = (lane < 8) ? wpB2[lane] : ~0ull;
            ull m1 = wmin64_16(a);
            ull bm = __ballot(a == m1);
            int lw = __ffsll((long long)bm) - 1;
            ull aa = (lane == lw) ? bb : a;
            ull m2 = wmin64_16(aa);
            if (lane == 0) {
                rowkey[i] = m1; rowkey2[i] = m2;
                atomicMin(&rm[(m + 1) & 1], (m1 & HIMASK) | (uint32_t)i);
                rm[m & 1] = ~0ull;                           // reset consumed slot
            }
        } else {
            for (int z = wave - 1; z < ncr; z += 7) {
                int r = list_l[z];
                int tsr = ts_l[r];
                const float* Rr = Db + (size_t)r * TN;
                ull a1r = ~0ull, a2r = ~0ull;
                #pragma unroll
                for (int q = 0; q < 16; ++q) {
                    int s = lane + q * 64;
                    if (!((aw[s >> 5] >> (s & 31)) & 1u) || s == r) continue;
                    float val;
                    if (s == i) val = Jl[slot * TN + r];
                    else {
                        int tss = ts_l[s];
                        int tm = (tss > tsr) ? tss : tsr;
                        val = (tm > m16) ? ((tss > tsr) ? Jl[(tss & 15) * TN + r]
                                                        : Jl[(tsr & 15) * TN + s])
                                         : Rr[s];
                    }
                    ull key = ((ull)f2sort(val) << 32) | (uint32_t)s;
                    if (key < a1r) { a2r = a1r; a1r = key; }
                    else if (key < a2r) a2r = key;
                }
                ull m1 = wmin64_all(a1r);
                ull bm = __ballot(a1r == m1);
                int lw = __ffsll((long long)bm) - 1;
                ull aa = (lane == lw) ? a2r : a1r;
                ull m2 = wmin64_all(aa);
                if (lane == 0) {
                    rowkey[r] = m1; rowkey2[r] = m2;
                    atomicMin(&rm[(m + 1) & 1], (m1 & HIMASK) | (uint32_t)r);
                }
            }
        }
        // deferred state updates by owner of element i
        if (e0 == i || e1 == i) {
            ts_l[i] = m; sizes_l[i] = ssum; wtarg[m & 7] = i;
        }

        // bar2: light barrier; every 8th iter full fence + race fix-up
        if ((m & 7) == 7) {
            FBAR();
            if (k < 64) {
                int t1 = k >> 3, t2 = k & 7;
                if (t1 != t2) {
                    int a = wtarg[t1], c = wtarg[t2];
                    if (a != c) {
                        bool lastA = true, lastC = true;
                        #pragma unroll
                        for (int t = 0; t < 8; ++t) {
                            if (t > t1 && wtarg[t] == a) lastA = false;
                            if (t > t2 && wtarg[t] == c) lastC = false;
                        }
                        if (lastA && lastC) {
                            int later = (t1 > t2) ? t1 : t2;
                            int earlier_i = (t1 > t2) ? c : a;
                            int iterlater = (m & ~7) + later;
                            float vv = Jl[(iterlater & 15) * TN + earlier_i];
                            Db[(size_t)a * TN + c] = vv;
                        }
                    }
                }
            }
            FBAR();
        } else {
            LBAR();
        }
    }

    // ---- epilogue: labels = rank of cluster root among active reps ----
    __syncthreads();
    if (k == 0) {
        int run = 0;
        for (int w = 0; w < 32; ++w) { woff[w] = run; run += __popc(aw[w]); }
    }
    __syncthreads();
    #pragma unroll
    for (int t = 0; t < 2; ++t) {
        int idx = k + 512 * t;
        int p = idx;
        while (!((aw[p >> 5] >> (p & 31)) & 1u)) p = parent_l[p];
        int rank = woff[p >> 5] + __popc(aw[p >> 5] & ((1u << (p & 31)) - 1u));
        out_labels[(size_t)b * TN + idx] = (float)rank;
    }
}

extern "C" void kernel_launch(void* const* d_in, const int* in_sizes, int n_in,
                              void* d_out, int out_size, void* d_ws, size_t ws_size,
                              hipStream_t stream) {
    const float* x = (const float*)d_in[0];
    float* out = (float*)d_out;

    float* xn      = (float*)d_ws;                          // NB*TN*CD floats
    float* Dwork   = xn + (size_t)NB * TN * CD;             // NB*TN*TN floats
    ull*   rowkey  = (ull*)(Dwork + (size_t)NB * TN * TN);  // NB*TN u64
    ull*   rowkey2 = rowkey + (size_t)NB * TN;              // NB*TN u64

    float* dist_out   = out;
    float* labels_out = out + (size_t)NB * TN * TN;

    norm_kernel<<<NB * TN, 256, 0, stream>>>(x, xn);
    dim3 g2(16, 16, NB);
    dist_kernel<<<g2, 256, 0, stream>>>(xn, dist_out, Dwork);
    rowmin_init_kernel<<<NB * TN, 256, 0, stream>>>(Dwork, rowkey, rowkey2);
    cluster_kernel<<<NB, 512, 0, stream>>>(Dwork, rowkey, rowkey2, labels_out);
}

// Round 9
// 4654.247 us; speedup vs baseline: 1.1032x; 1.0824x over previous
//
#include <hip/hip_runtime.h>
#include <stdint.h>

#define TN 1024
#define CD 192
#define NB 8
#define NCLUST 196
#define NMERGE (TN - NCLUST)
#define HIMASK 0xFFFFFFFF00000000ull

typedef unsigned long long ull;

// Workgroup barrier WITHOUT global-memory drain (LDS made visible only).
#define LBAR() asm volatile("s_waitcnt lgkmcnt(0)\n\ts_barrier" ::: "memory")
// Full fence barrier: drains global stores too.
#define FBAR() asm volatile("s_waitcnt vmcnt(0) lgkmcnt(0)\n\ts_barrier" ::: "memory")

__device__ __forceinline__ uint32_t f2sort(float f) {
    uint32_t u = __float_as_uint(f);
    return u ^ ((u >> 31) ? 0xFFFFFFFFu : 0x80000000u);
}

template<int CTRL>
__device__ __forceinline__ uint32_t dpp_min32(uint32_t x) {
    uint32_t t = (uint32_t)__builtin_amdgcn_update_dpp((int)x, (int)x, CTRL, 0xF, 0xF, false);
    return (t < x) ? t : x;
}
template<int CTRL>
__device__ __forceinline__ ull dpp_min64(ull x) {
    int lo = (int)(uint32_t)x, hi = (int)(uint32_t)(x >> 32);
    int tlo = __builtin_amdgcn_update_dpp(lo, lo, CTRL, 0xF, 0xF, false);
    int thi = __builtin_amdgcn_update_dpp(hi, hi, CTRL, 0xF, 0xF, false);
    ull t = ((ull)(uint32_t)thi << 32) | (uint32_t)tlo;
    return (t < x) ? t : x;
}
__device__ __forceinline__ uint32_t wmin32_all(uint32_t x) {
    x = dpp_min32<0x111>(x); x = dpp_min32<0x112>(x);
    x = dpp_min32<0x114>(x); x = dpp_min32<0x118>(x);
    x = dpp_min32<0x142>(x); x = dpp_min32<0x143>(x);
    return (uint32_t)__builtin_amdgcn_readlane((int)x, 63);
}
__device__ __forceinline__ ull wmin64_all(ull x) {
    x = dpp_min64<0x111>(x); x = dpp_min64<0x112>(x);
    x = dpp_min64<0x114>(x); x = dpp_min64<0x118>(x);
    x = dpp_min64<0x142>(x); x = dpp_min64<0x143>(x);
    int lo = __builtin_amdgcn_readlane((int)(uint32_t)x, 63);
    int hi = __builtin_amdgcn_readlane((int)(uint32_t)(x >> 32), 63);
    return ((ull)(uint32_t)hi << 32) | (uint32_t)lo;
}
// min over lanes 0..15 (lanes 16+ must hold ~0), broadcast
__device__ __forceinline__ ull wmin64_16(ull x) {
    x = dpp_min64<0x111>(x); x = dpp_min64<0x112>(x);
    x = dpp_min64<0x114>(x); x = dpp_min64<0x118>(x);
    int lo = __builtin_amdgcn_readlane((int)(uint32_t)x, 15);
    int hi = __builtin_amdgcn_readlane((int)(uint32_t)(x >> 32), 15);
    return ((ull)(uint32_t)hi << 32) | (uint32_t)lo;
}

__device__ __forceinline__ ull shfl_min_ull(ull v) {   // init kernels only
    #pragma unroll
    for (int off = 32; off > 0; off >>= 1) {
        ull o = (ull)__shfl_xor((long long)v, off, 64);
        if (o < v) v = o;
    }
    return v;
}

// ---------------- normalize rows: xn = x / ||x|| ----------------
__global__ void norm_kernel(const float* __restrict__ x, float* __restrict__ xn) {
    int row = blockIdx.x;
    int t = threadIdx.x;
    __shared__ float ssum[4];
    float v = 0.f;
    if (t < CD) v = x[(size_t)row * CD + t];
    float s = v * v;
    #pragma unroll
    for (int off = 32; off > 0; off >>= 1) s += __shfl_xor(s, off, 64);
    if ((t & 63) == 0) ssum[t >> 6] = s;
    __syncthreads();
    float tot = ssum[0] + ssum[1] + ssum[2] + ssum[3];
    float nrm = __fsqrt_rn(tot);
    if (t < CD) xn[(size_t)row * CD + t] = __fdiv_rn(v, nrm);
}

// ---------------- dist = 1 - xn @ xn^T, 64x64 tiles ----------------
#define KC 32
__global__ __launch_bounds__(256) void dist_kernel(const float* __restrict__ xn,
                                                   float* __restrict__ dout,
                                                   float* __restrict__ dwork) {
    int b = blockIdx.z;
    int bm = blockIdx.y, bn = blockIdx.x;
    const float* X = xn + (size_t)b * TN * CD;
    __shared__ float As[KC][68];
    __shared__ float Bs[KC][68];
    int tid = threadIdx.x;
    int tx = tid & 15, ty = tid >> 4;
    int lr = tid >> 2;
    int lq = tid & 3;
    float acc[4][4];
    #pragma unroll
    for (int r = 0; r < 4; ++r)
        #pragma unroll
        for (int c = 0; c < 4; ++c) acc[r][c] = 0.f;

    for (int kc = 0; kc < CD; kc += KC) {
        float4 a0 = *(const float4*)&X[(size_t)(bm * 64 + lr) * CD + kc + lq * 4];
        float4 a1 = *(const float4*)&X[(size_t)(bm * 64 + lr) * CD + kc + (lq + 4) * 4];
        float4 b0 = *(const float4*)&X[(size_t)(bn * 64 + lr) * CD + kc + lq * 4];
        float4 b1 = *(const float4*)&X[(size_t)(bn * 64 + lr) * CD + kc + (lq + 4) * 4];
        __syncthreads();
        As[lq * 4 + 0][lr] = a0.x; As[lq * 4 + 1][lr] = a0.y;
        As[lq * 4 + 2][lr] = a0.z; As[lq * 4 + 3][lr] = a0.w;
        As[lq * 4 + 16][lr] = a1.x; As[lq * 4 + 17][lr] = a1.y;
        As[lq * 4 + 18][lr] = a1.z; As[lq * 4 + 19][lr] = a1.w;
        Bs[lq * 4 + 0][lr] = b0.x; Bs[lq * 4 + 1][lr] = b0.y;
        Bs[lq * 4 + 2][lr] = b0.z; Bs[lq * 4 + 3][lr] = b0.w;
        Bs[lq * 4 + 16][lr] = b1.x; Bs[lq * 4 + 17][lr] = b1.y;
        Bs[lq * 4 + 18][lr] = b1.z; Bs[lq * 4 + 19][lr] = b1.w;
        __syncthreads();
        #pragma unroll
        for (int kk = 0; kk < KC; ++kk) {
            float4 av = *(const float4*)&As[kk][ty * 4];
            float4 bv = *(const float4*)&Bs[kk][tx * 4];
            acc[0][0] += av.x * bv.x; acc[0][1] += av.x * bv.y;
            acc[0][2] += av.x * bv.z; acc[0][3] += av.x * bv.w;
            acc[1][0] += av.y * bv.x; acc[1][1] += av.y * bv.y;
            acc[1][2] += av.y * bv.z; acc[1][3] += av.y * bv.w;
            acc[2][0] += av.z * bv.x; acc[2][1] += av.z * bv.y;
            acc[2][2] += av.z * bv.z; acc[2][3] += av.z * bv.w;
            acc[3][0] += av.w * bv.x; acc[3][1] += av.w * bv.y;
            acc[3][2] += av.w * bv.z; acc[3][3] += av.w * bv.w;
        }
    }
    size_t obase = (size_t)b * TN * TN;
    #pragma unroll
    for (int r = 0; r < 4; ++r) {
        int mrow = bm * 64 + ty * 4 + r;
        float4 o;
        o.x = 1.0f - acc[r][0]; o.y = 1.0f - acc[r][1];
        o.z = 1.0f - acc[r][2]; o.w = 1.0f - acc[r][3];
        size_t idx = obase + (size_t)mrow * TN + bn * 64 + tx * 4;
        *(float4*)&dout[idx] = o;
        *(float4*)&dwork[idx] = o;
    }
}

// ---------------- per-row top-2 init ----------------
__global__ void rowmin_init_kernel(const float* __restrict__ D,
                                   ull* __restrict__ rowkey, ull* __restrict__ rowkey2) {
    int gid = blockIdx.x;
    int bb = gid >> 10, r = gid & 1023;
    const float* Drow = D + (size_t)bb * TN * TN + (size_t)r * TN;
    int t = threadIdx.x;
    __shared__ ull part[4];
    __shared__ ull m1s;
    ull k = ~0ull;
    for (int s = t; s < TN; s += 256) {
        if (s != r) {
            ull key = ((ull)f2sort(Drow[s]) << 32) | (uint32_t)s;
            if (key < k) k = key;
        }
    }
    k = shfl_min_ull(k);
    if ((t & 63) == 0) part[t >> 6] = k;
    __syncthreads();
    if (t == 0) {
        ull m = part[0];
        #pragma unroll
        for (int w = 1; w < 4; ++w) if (part[w] < m) m = part[w];
        rowkey[gid] = m;
        m1s = m;
    }
    __syncthreads();
    ull m1 = m1s;
    int c1 = (int)(uint32_t)m1;
    ull k2 = ~0ull;
    for (int s = t; s < TN; s += 256) {
        if (s != r && s != c1) {
            ull key = ((ull)f2sort(Drow[s]) << 32) | (uint32_t)s;
            if (key < k2) k2 = key;
        }
    }
    k2 = shfl_min_ull(k2);
    __syncthreads();
    if ((t & 63) == 0) part[t >> 6] = k2;
    __syncthreads();
    if (t == 0) {
        ull m = part[0];
        #pragma unroll
        for (int w = 1; w < 4; ++w) if (part[w] < m) m = part[w];
        rowkey2[gid] = m;
    }
}

// ---------------- clustering: 16 waves, 1 elem/thread, 2 barriers/iter ----------------
// Region X: redundant final-min (wpA[16]+rm), Phase B (journal bridge), fused row-i
// top-2 partials, Phase D top-2 maintenance (thread j poisons j), A-partials for m+1
// from post-D registers, global stores last. Region Y: wave0 finalizes row-i top-2
// (-> rowkey[i], rm); waves 1-15 rescan pending rows (-> rm); owner thread i applies
// ts/sizes/wtarg. Journal bridge / FBAR-every-8 + race fixup identical to R5/R6.
__global__ __launch_bounds__(1024) void cluster_kernel(float* __restrict__ D,
                                                       const ull* __restrict__ rk_init,
                                                       const ull* __restrict__ rk2_init,
                                                       float* __restrict__ out_labels) {
    int b = blockIdx.x;
    float* Db = D + (size_t)b * TN * TN;
    int k = threadIdx.x;               // 0..1023, owns element k
    int lane = k & 63, wave = k >> 6;  // 16 waves

    __shared__ float Jl[16 * TN];      // 64 KB journal ring
    __shared__ ull rowkey[TN];         // min1 key: (val<<32)|col ; ~0 = dead/pending
    __shared__ ull rowkey2[TN];        // min2 key or ~0 = unknown
    __shared__ float sizes_l[TN];
    __shared__ int ts_l[TN];
    __shared__ int parent_l[TN];
    __shared__ uint32_t aw[TN / 32];
    __shared__ int list_l[TN];
    __shared__ int nrecb[2];
    __shared__ ull rm[2];              // fresh keys of row-i / rescanned rows
    __shared__ ull wpA[16], wpB1[16], wpB2[16];
    __shared__ int wtarg[8];
    __shared__ int prefix_w[16], woff[16];

    rowkey[k] = rk_init[b * TN + k];
    rowkey2[k] = rk2_init[b * TN + k];
    sizes_l[k] = 1.0f;
    ts_l[k] = -1000000;
    parent_l[k] = k;
    if (k < TN / 32) aw[k] = 0xFFFFFFFFu;
    if (k < 2) { nrecb[k] = 0; rm[k] = ~0ull; }
    __syncthreads();

    // prologue: A-partials for m=0 (32-bit DPP + ballot)
    {
        uint32_t v32 = (uint32_t)(rowkey[k] >> 32);
        uint32_t vm = wmin32_all(v32);
        ull bm = __ballot(v32 == vm);
        int lm = __ffsll((long long)bm) - 1;
        if (lane == 0) wpA[wave] = ((ull)vm << 32) | (uint32_t)(wave * 64 + lm);
    }
    __syncthreads();

    for (int m = 0; m < NMERGE; ++m) {
        int m16 = m - 16;
        int slot = m & 15;

        // =================== region X ===================
        // final-min, redundant in every wave
        ull v = (lane < 16) ? wpA[lane] : ~0ull;
        {
            ull rmv = rm[m & 1];
            if (lane == 0 && rmv < v) v = rmv;
        }
        ull g = wmin64_16(v);
        int i = (int)(uint32_t)g;
        int j = (int)(uint32_t)rowkey[i];
        float ni = sizes_l[i], nj = sizes_l[j];
        int tsi = ts_l[i], tsj = ts_l[j];
        float ssum = __fadd_rn(ni, nj);

        ull K0 = rowkey[k];
        ull M0 = rowkey2[k];
        int tsk = ts_l[k];

        // Phase B: fresh rows i,j (uniform journal fast path)
        float di, dj;
        if (tsi > m16) {
            di = (tsk > tsi) ? Jl[(tsk & 15) * TN + i] : Jl[(tsi & 15) * TN + k];
        } else {
            float gv = Db[(size_t)i * TN + k];
            di = (tsk > m16) ? Jl[(tsk & 15) * TN + i] : gv;
        }
        if (tsj > m16) {
            dj = (tsk > tsj) ? Jl[(tsk & 15) * TN + j] : Jl[(tsj & 15) * TN + k];
        } else {
            float gv = Db[(size_t)j * TN + k];
            dj = (tsk > m16) ? Jl[(tsk & 15) * TN + j] : gv;
        }
        float nr = __fdiv_rn(__fadd_rn(__fmul_rn(ni, di), __fmul_rn(nj, dj)), ssum);
        Jl[slot * TN + k] = nr;                            // journal (LDS)

        // fused row-i top-2 partials (32-bit DPP + ballot, as R6)
        bool alive = (K0 != ~0ull && k != i && k != j);
        uint32_t cv = alive ? f2sort(nr) : 0xFFFFFFFFu;
        {
            uint32_t w1 = wmin32_all(cv);
            ull b1m = __ballot(cv == w1);
            int l1 = __ffsll((long long)b1m) - 1;
            uint32_t cv2 = (lane == l1) ? 0xFFFFFFFFu : cv;
            uint32_t w2 = wmin32_all(cv2);
            ull b2m = __ballot(cv2 == w2);
            int l2 = __ffsll((long long)b2m) - 1;
            if (lane == 0) {
                wpB1[wave] = ((ull)w1 << 32) | (uint32_t)(wave * 64 + l1);
                wpB2[wave] = ((ull)w2 << 32) | (uint32_t)(wave * 64 + l2);
            }
        }

        // Phase D: top-2 incremental maintenance; nK = post-D min1 key (~0 = dead/pending)
        ull nK;
        if (!alive) {
            if (k == j) {                                  // owner poisons j
                rowkey[k] = ~0ull; rowkey2[k] = ~0ull;
                parent_l[k] = i;
                aw[k >> 5] &= ~(1u << (k & 31));
            }
            nK = ~0ull;
        } else {
            ull nk = ((ull)f2sort(nr) << 32) | (uint32_t)i;
            uint32_t c1 = (uint32_t)K0;
            bool k1 = (c1 == (uint32_t)i) || (c1 == (uint32_t)j);
            bool mvalid = (M0 != ~0ull);
            if (mvalid) {
                uint32_t c2 = (uint32_t)M0;
                if (c2 == (uint32_t)i || c2 == (uint32_t)j) mvalid = false;
            }
            if (!k1) {
                if (nk < K0) { rowkey[k] = nk; rowkey2[k] = K0; nK = nk; }
                else { rowkey2[k] = mvalid ? ((nk < M0) ? nk : M0) : ~0ull; nK = K0; }
            } else {
                if (mvalid) {
                    if (nk < M0) { rowkey[k] = nk; rowkey2[k] = M0; nK = nk; }
                    else { rowkey[k] = M0; rowkey2[k] = ~0ull; nK = M0; }
                } else {
                    rowkey[k] = ~0ull; rowkey2[k] = ~0ull;   // pending rescan
                    int idx = atomicAdd(&nrecb[m & 1], 1); list_l[idx] = k;
                    nK = ~0ull;
                }
            }
        }

        // A-partials for merge m+1 (from post-D registers; i routed via rm)
        {
            uint32_t v32 = (uint32_t)(nK >> 32);
            uint32_t vm = wmin32_all(v32);
            ull bm = __ballot(v32 == vm);
            int lm = __ffsll((long long)bm) - 1;
            if (lane == 0) wpA[wave] = ((ull)vm << 32) | (uint32_t)(wave * 64 + lm);
        }
        if (k == 0) nrecb[(m & 1) ^ 1] = 0;

        // global stores last: coalesced row i + fire-and-forget scattered col i
        Db[(size_t)i * TN + k] = nr;
        if (K0 != ~0ull) Db[(size_t)k * TN + i] = nr;

        LBAR();                                            // bar1

        // =================== region Y ===================
        int ncr = nrecb[m & 1];
        if (wave == 0) {
            // finalize row i's top-2 from the 16 wave partials
            ull a = (lane < 16) ? wpB1[lane] : ~0ull;
            ull bb = (lane < 16) ? wpB2[lane] : ~0ull;
            ull m1 = wmin64_16(a);
            ull bm = __ballot(a == m1);
            int lw = __ffsll((long long)bm) - 1;
            ull aa = (lane == lw) ? bb : a;
            ull m2 = wmin64_16(aa);
            if (lane == 0) {
                rowkey[i] = m1; rowkey2[i] = m2;
                atomicMin(&rm[(m + 1) & 1], (m1 & HIMASK) | (uint32_t)i);
                rm[m & 1] = ~0ull;                         // reset consumed slot
            }
        } else {
            for (int z = wave - 1; z < ncr; z += 15) {
                int r = list_l[z];
                int tsr = ts_l[r];
                const float* Rr = Db + (size_t)r * TN;
                ull a1r = ~0ull, a2r = ~0ull;
                #pragma unroll
                for (int q = 0; q < 16; ++q) {
                    int s = lane + q * 64;
                    if (!((aw[s >> 5] >> (s & 31)) & 1u) || s == r) continue;
                    float val;
                    if (s == i) val = Jl[slot * TN + r];
                    else {
                        int tss = ts_l[s];
                        int tm = (tss > tsr) ? tss : tsr;
                        val = (tm > m16) ? ((tss > tsr) ? Jl[(tss & 15) * TN + r]
                                                        : Jl[(tsr & 15) * TN + s])
                                         : Rr[s];
                    }
                    ull key = ((ull)f2sort(val) << 32) | (uint32_t)s;
                    if (key < a1r) { a2r = a1r; a1r = key; }
                    else if (key < a2r) a2r = key;
                }
                ull m1 = wmin64_all(a1r);
                ull bm = __ballot(a1r == m1);
                int lw = __ffsll((long long)bm) - 1;
                ull aa = (lane == lw) ? a2r : a1r;
                ull m2 = wmin64_all(aa);
                if (lane == 0) {
                    rowkey[r] = m1; rowkey2[r] = m2;
                    atomicMin(&rm[(m + 1) & 1], (m1 & HIMASK) | (uint32_t)r);
                }
            }
        }
        // deferred state updates by owner of element i
        if (k == i) { ts_l[i] = m; sizes_l[i] = ssum; wtarg[m & 7] = i; }

        // bar2: light barrier; every 8th iter full fence + race fix-up
        if ((m & 7) == 7) {
            FBAR();
            if (k < 64) {
                int t1 = k >> 3, t2 = k & 7;
                if (t1 != t2) {
                    int a = wtarg[t1], c = wtarg[t2];
                    if (a != c) {
                        bool lastA = true, lastC = true;
                        #pragma unroll
                        for (int t = 0; t < 8; ++t) {
                            if (t > t1 && wtarg[t] == a) lastA = false;
                            if (t > t2 && wtarg[t] == c) lastC = false;
                        }
                        if (lastA && lastC) {
                            int later = (t1 > t2) ? t1 : t2;
                            int earlier_i = (t1 > t2) ? c : a;
                            int iterlater = (m & ~7) + later;
                            float vv = Jl[(iterlater & 15) * TN + earlier_i];
                            Db[(size_t)a * TN + c] = vv;
                        }
                    }
                }
            }
            FBAR();
        } else {
            LBAR();
        }
    }

    // ---- epilogue: labels = rank of cluster root among active reps ----
    __syncthreads();
    int a = (aw[k >> 5] >> (k & 31)) & 1;
    ull mask = __ballot(a);
    int lanepre = __popcll(mask & (((ull)1 << lane) - 1ull));
    if (lane == 0) prefix_w[wave] = __popcll(mask);
    __syncthreads();
    if (k == 0) {
        int run = 0;
        for (int w2 = 0; w2 < 16; ++w2) { woff[w2] = run; run += prefix_w[w2]; }
    }
    __syncthreads();
    list_l[k] = woff[wave] + lanepre;
    __syncthreads();
    int p = k;
    while (!((aw[p >> 5] >> (p & 31)) & 1u)) p = parent_l[p];
    out_labels[(size_t)b * TN + k] = (float)list_l[p];
}

extern "C" void kernel_launch(void* const* d_in, const int* in_sizes, int n_in,
                              void* d_out, int out_size, void* d_ws, size_t ws_size,
                              hipStream_t stream) {
    const float* x = (const float*)d_in[0];
    float* out = (float*)d_out;

    float* xn      = (float*)d_ws;                          // NB*TN*CD floats
    float* Dwork   = xn + (size_t)NB * TN * CD;             // NB*TN*TN floats
    ull*   rowkey  = (ull*)(Dwork + (size_t)NB * TN * TN);  // NB*TN u64
    ull*   rowkey2 = rowkey + (size_t)NB * TN;              // NB*TN u64

    float* dist_out   = out;
    float* labels_out = out + (size_t)NB * TN * TN;

    norm_kernel<<<NB * TN, 256, 0, stream>>>(x, xn);
    dim3 g2(16, 16, NB);
    dist_kernel<<<g2, 256, 0, stream>>>(xn, dist_out, Dwork);
    rowmin_init_kernel<<<NB * TN, 256, 0, stream>>>(Dwork, rowkey, rowkey2);
    cluster_kernel<<<NB, 1024, 0, stream>>>(Dwork, rowkey, rowkey2, labels_out);
}

// Round 10
// 3278.918 us; speedup vs baseline: 1.5660x; 1.4194x over previous
//
#include <hip/hip_runtime.h>
#include <stdint.h>

#define TN 1024
#define CD 192
#define NB 8
#define NCLUST 196
#define NMERGE (TN - NCLUST)
#define FWIN 15          // fence window (< journal depth 16)

typedef unsigned long long ull;

// Workgroup barrier WITHOUT global-memory drain (LDS made visible only).
#define LBAR() asm volatile("s_waitcnt lgkmcnt(0)\n\ts_barrier" ::: "memory")
// Full fence barrier: drains global stores too.
#define FBAR() asm volatile("s_waitcnt vmcnt(0) lgkmcnt(0)\n\ts_barrier" ::: "memory")

__device__ __forceinline__ uint32_t f2sort(float f) {
    uint32_t u = __float_as_uint(f);
    return u ^ ((u >> 31) ? 0xFFFFFFFFu : 0x80000000u);
}

// ---------- DPP min-reductions ----------
template<int CTRL>
__device__ __forceinline__ uint32_t dpp_min32(uint32_t x) {
    uint32_t t = (uint32_t)__builtin_amdgcn_update_dpp((int)x, (int)x, CTRL, 0xF, 0xF, false);
    return (t < x) ? t : x;
}
template<int CTRL>
__device__ __forceinline__ ull dpp_min64(ull x) {
    int lo = (int)(uint32_t)x, hi = (int)(uint32_t)(x >> 32);
    int tlo = __builtin_amdgcn_update_dpp(lo, lo, CTRL, 0xF, 0xF, false);
    int thi = __builtin_amdgcn_update_dpp(hi, hi, CTRL, 0xF, 0xF, false);
    ull t = ((ull)(uint32_t)thi << 32) | (uint32_t)tlo;
    return (t < x) ? t : x;
}
__device__ __forceinline__ uint32_t wmin32_all(uint32_t x) {
    x = dpp_min32<0x111>(x); x = dpp_min32<0x112>(x);
    x = dpp_min32<0x114>(x); x = dpp_min32<0x118>(x);
    x = dpp_min32<0x142>(x); x = dpp_min32<0x143>(x);
    return (uint32_t)__builtin_amdgcn_readlane((int)x, 63);
}
__device__ __forceinline__ ull wmin64_all(ull x) {
    x = dpp_min64<0x111>(x); x = dpp_min64<0x112>(x);
    x = dpp_min64<0x114>(x); x = dpp_min64<0x118>(x);
    x = dpp_min64<0x142>(x); x = dpp_min64<0x143>(x);
    int lo = __builtin_amdgcn_readlane((int)(uint32_t)x, 63);
    int hi = __builtin_amdgcn_readlane((int)(uint32_t)(x >> 32), 63);
    return ((ull)(uint32_t)hi << 32) | (uint32_t)lo;
}
// min over lanes 0..15 (others must hold ~0), broadcast
__device__ __forceinline__ ull wmin64_16(ull x) {
    x = dpp_min64<0x111>(x); x = dpp_min64<0x112>(x);
    x = dpp_min64<0x114>(x); x = dpp_min64<0x118>(x);
    int lo = __builtin_amdgcn_readlane((int)(uint32_t)x, 15);
    int hi = __builtin_amdgcn_readlane((int)(uint32_t)(x >> 32), 15);
    return ((ull)(uint32_t)hi << 32) | (uint32_t)lo;
}

__device__ __forceinline__ ull shfl_min_ull(ull v) {   // init kernels only
    #pragma unroll
    for (int off = 32; off > 0; off >>= 1) {
        ull o = (ull)__shfl_xor((long long)v, off, 64);
        if (o < v) v = o;
    }
    return v;
}

// ---------------- normalize rows: xn = x / ||x|| ----------------
__global__ void norm_kernel(const float* __restrict__ x, float* __restrict__ xn) {
    int row = blockIdx.x;
    int t = threadIdx.x;
    __shared__ float ssum[4];
    float v = 0.f;
    if (t < CD) v = x[(size_t)row * CD + t];
    float s = v * v;
    #pragma unroll
    for (int off = 32; off > 0; off >>= 1) s += __shfl_xor(s, off, 64);
    if ((t & 63) == 0) ssum[t >> 6] = s;
    __syncthreads();
    float tot = ssum[0] + ssum[1] + ssum[2] + ssum[3];
    float nrm = __fsqrt_rn(tot);
    if (t < CD) xn[(size_t)row * CD + t] = __fdiv_rn(v, nrm);
}

// ---------------- dist = 1 - xn @ xn^T, 64x64 tiles ----------------
#define KC 32
__global__ __launch_bounds__(256) void dist_kernel(const float* __restrict__ xn,
                                                   float* __restrict__ dout,
                                                   float* __restrict__ dwork) {
    int b = blockIdx.z;
    int bm = blockIdx.y, bn = blockIdx.x;
    const float* X = xn + (size_t)b * TN * CD;
    __shared__ float As[KC][68];
    __shared__ float Bs[KC][68];
    int tid = threadIdx.x;
    int tx = tid & 15, ty = tid >> 4;
    int lr = tid >> 2;
    int lq = tid & 3;
    float acc[4][4];
    #pragma unroll
    for (int r = 0; r < 4; ++r)
        #pragma unroll
        for (int c = 0; c < 4; ++c) acc[r][c] = 0.f;

    for (int kc = 0; kc < CD; kc += KC) {
        float4 a0 = *(const float4*)&X[(size_t)(bm * 64 + lr) * CD + kc + lq * 4];
        float4 a1 = *(const float4*)&X[(size_t)(bm * 64 + lr) * CD + kc + (lq + 4) * 4];
        float4 b0 = *(const float4*)&X[(size_t)(bn * 64 + lr) * CD + kc + lq * 4];
        float4 b1 = *(const float4*)&X[(size_t)(bn * 64 + lr) * CD + kc + (lq + 4) * 4];
        __syncthreads();
        As[lq * 4 + 0][lr] = a0.x; As[lq * 4 + 1][lr] = a0.y;
        As[lq * 4 + 2][lr] = a0.z; As[lq * 4 + 3][lr] = a0.w;
        As[lq * 4 + 16][lr] = a1.x; As[lq * 4 + 17][lr] = a1.y;
        As[lq * 4 + 18][lr] = a1.z; As[lq * 4 + 19][lr] = a1.w;
        Bs[lq * 4 + 0][lr] = b0.x; Bs[lq * 4 + 1][lr] = b0.y;
        Bs[lq * 4 + 2][lr] = b0.z; Bs[lq * 4 + 3][lr] = b0.w;
        Bs[lq * 4 + 16][lr] = b1.x; Bs[lq * 4 + 17][lr] = b1.y;
        Bs[lq * 4 + 18][lr] = b1.z; Bs[lq * 4 + 19][lr] = b1.w;
        __syncthreads();
        #pragma unroll
        for (int kk = 0; kk < KC; ++kk) {
            float4 av = *(const float4*)&As[kk][ty * 4];
            float4 bv = *(const float4*)&Bs[kk][tx * 4];
            acc[0][0] += av.x * bv.x; acc[0][1] += av.x * bv.y;
            acc[0][2] += av.x * bv.z; acc[0][3] += av.x * bv.w;
            acc[1][0] += av.y * bv.x; acc[1][1] += av.y * bv.y;
            acc[1][2] += av.y * bv.z; acc[1][3] += av.y * bv.w;
            acc[2][0] += av.z * bv.x; acc[2][1] += av.z * bv.y;
            acc[2][2] += av.z * bv.z; acc[2][3] += av.z * bv.w;
            acc[3][0] += av.w * bv.x; acc[3][1] += av.w * bv.y;
            acc[3][2] += av.w * bv.z; acc[3][3] += av.w * bv.w;
        }
    }
    size_t obase = (size_t)b * TN * TN;
    #pragma unroll
    for (int r = 0; r < 4; ++r) {
        int mrow = bm * 64 + ty * 4 + r;
        float4 o;
        o.x = 1.0f - acc[r][0]; o.y = 1.0f - acc[r][1];
        o.z = 1.0f - acc[r][2]; o.w = 1.0f - acc[r][3];
        size_t idx = obase + (size_t)mrow * TN + bn * 64 + tx * 4;
        *(float4*)&dout[idx] = o;
        *(float4*)&dwork[idx] = o;
    }
}

// ---------------- per-row top-2 init ----------------
__global__ void rowmin_init_kernel(const float* __restrict__ D,
                                   ull* __restrict__ rowkey, ull* __restrict__ rowkey2) {
    int gid = blockIdx.x;
    int bb = gid >> 10, r = gid & 1023;
    const float* Drow = D + (size_t)bb * TN * TN + (size_t)r * TN;
    int t = threadIdx.x;
    __shared__ ull part[4];
    __shared__ ull m1s;
    ull k = ~0ull;
    for (int s = t; s < TN; s += 256) {
        if (s != r) {
            ull key = ((ull)f2sort(Drow[s]) << 32) | (uint32_t)s;
            if (key < k) k = key;
        }
    }
    k = shfl_min_ull(k);
    if ((t & 63) == 0) part[t >> 6] = k;
    __syncthreads();
    if (t == 0) {
        ull m = part[0];
        #pragma unroll
        for (int w = 1; w < 4; ++w) if (part[w] < m) m = part[w];
        rowkey[gid] = m;
        m1s = m;
    }
    __syncthreads();
    ull m1 = m1s;
    int c1 = (int)(uint32_t)m1;
    ull k2 = ~0ull;
    for (int s = t; s < TN; s += 256) {
        if (s != r && s != c1) {
            ull key = ((ull)f2sort(Drow[s]) << 32) | (uint32_t)s;
            if (key < k2) k2 = key;
        }
    }
    k2 = shfl_min_ull(k2);
    __syncthreads();
    if ((t & 63) == 0) part[t >> 6] = k2;
    __syncthreads();
    if (t == 0) {
        ull m = part[0];
        #pragma unroll
        for (int w = 1; w < 4; ++w) if (part[w] < m) m = part[w];
        rowkey2[gid] = m;
    }
}

// ---------------- agglomerative clustering: 16 waves/batch (R6 structure) ----------------
// Journal bridge + light barriers + FBAR-every-FWIN + race fixup; DPP reductions,
// uniform-branch journal fast path, top-2 rowkey, fused row-i top-2.
__global__ __launch_bounds__(1024) void cluster_kernel(float* __restrict__ D,
                                                       const ull* __restrict__ rk_init,
                                                       const ull* __restrict__ rk2_init,
                                                       float* __restrict__ out_labels) {
    int b = blockIdx.x;
    float* Db = D + (size_t)b * TN * TN;
    int k = threadIdx.x;
    int lane = k & 63, wave = k >> 6;

    __shared__ float Jl[16 * TN];        // 64 KB journal ring of last 16 merged rows
    __shared__ ull rowkey[TN];           // min1: (sortable val << 32) | col; ~0 = dead
    __shared__ ull rowkey2[TN];          // min2 or ~0 = unknown
    __shared__ float sizes_l[TN];
    __shared__ int ts_l[TN] __attribute__((aligned(16)));
    __shared__ int parent_l[TN];
    __shared__ uint32_t aw[TN / 32];
    __shared__ int list_l[TN];
    __shared__ int nrecb[2];
    __shared__ ull wpA[16], wpB1[16], wpB2[16];
    __shared__ int bc_i, bc_j, bc_tsi, bc_tsj;
    __shared__ float bc_ni, bc_nj;
    __shared__ int wtarg[FWIN];
    __shared__ int prefix_w[16], woff[16];

    rowkey[k] = rk_init[b * TN + k];
    rowkey2[k] = rk2_init[b * TN + k];
    sizes_l[k] = 1.0f;
    ts_l[k] = -1000000;
    parent_l[k] = k;
    if (k < TN / 32) aw[k] = 0xFFFFFFFFu;
    if (k < 2) nrecb[k] = 0;
    __syncthreads();

    for (int m = 0; m < NMERGE; ++m) {
        int m16 = m - 16;
        int mw = m % FWIN;

        // ---- Phase A: global argmin (val, row) via DPP + ballot ----
        ull K0 = rowkey[k];
        uint32_t v32 = (uint32_t)(K0 >> 32);
        uint32_t vm = wmin32_all(v32);
        ull bmA = __ballot(v32 == vm);
        int lm = __ffsll((long long)bmA) - 1;
        if (lane == 0) wpA[wave] = ((ull)vm << 32) | (uint32_t)(wave * 64 + lm);
        LBAR();                                            // bar1
        if (wave == 0) {
            ull t = (lane < 16) ? wpA[lane] : ~0ull;
            ull g = wmin64_16(t);
            if (lane == 0) {
                int i = (int)(uint32_t)g;
                int j = (int)(uint32_t)rowkey[i];
                bc_i = i; bc_j = j;
                bc_tsi = ts_l[i]; bc_tsj = ts_l[j];
                float ni = sizes_l[i], nj = sizes_l[j];
                bc_ni = ni; bc_nj = nj;
                sizes_l[i] = __fadd_rn(ni, nj);
                ts_l[i] = m;
                rowkey[j] = ~0ull;
                rowkey2[j] = ~0ull;
                parent_l[j] = i;
                aw[j >> 5] &= ~(1u << (j & 31));
                wtarg[mw] = i;
                nrecb[(m & 1) ^ 1] = 0;
            }
        }
        LBAR();                                            // bar2
        int i = bc_i, j = bc_j;
        int tsi = bc_tsi, tsj = bc_tsj;
        float ni = bc_ni, nj = bc_nj;
        float ssum = __fadd_rn(ni, nj);

        // ---- Phase B: fresh rows i,j; uniform branch skips global load when
        //      the whole row lives in the LDS journal ----
        int tsk = ts_l[k];
        float di, dj;
        if (tsi > m16) {
            di = (tsk > tsi) ? Jl[(tsk & 15) * TN + i] : Jl[(tsi & 15) * TN + k];
        } else {
            di = (tsk > m16) ? Jl[(tsk & 15) * TN + i] : Db[(size_t)i * TN + k];
        }
        if (tsj > m16) {
            dj = (tsk > tsj) ? Jl[(tsk & 15) * TN + j] : Jl[(tsj & 15) * TN + k];
        } else {
            dj = (tsk > m16) ? Jl[(tsk & 15) * TN + j] : Db[(size_t)j * TN + k];
        }
        float nr = __fdiv_rn(__fadd_rn(__fmul_rn(ni, di), __fmul_rn(nj, dj)), ssum);
        Jl[(m & 15) * TN + k] = nr;                        // journal (LDS)
        Db[(size_t)i * TN + k] = nr;                       // coalesced row write
        if (K0 != ~0ull) Db[(size_t)k * TN + i] = nr;      // scattered col write (live only)

        // ---- fused row-i NN: per-wave top-2 of nr (2 ballot-DPP passes) ----
        uint32_t cv = (K0 != ~0ull && k != i && k != j) ? f2sort(nr) : 0xFFFFFFFFu;
        uint32_t w1 = wmin32_all(cv);
        ull b1m = __ballot(cv == w1);
        int l1 = __ffsll((long long)b1m) - 1;
        uint32_t cv2 = (lane == l1) ? 0xFFFFFFFFu : cv;
        uint32_t w2 = wmin32_all(cv2);
        ull b2m = __ballot(cv2 == w2);
        int l2 = __ffsll((long long)b2m) - 1;
        if (lane == 0) {
            wpB1[wave] = ((ull)w1 << 32) | (uint32_t)(wave * 64 + l1);
            wpB2[wave] = ((ull)w2 << 32) | (uint32_t)(wave * 64 + l2);
        }

        // ---- Phase D: top-2 incremental maintenance ----
        if (K0 != ~0ull && k != i && k != j) {
            ull M0 = rowkey2[k];
            uint32_t c1 = (uint32_t)K0;
            ull nk = ((ull)f2sort(nr) << 32) | (uint32_t)i;
            bool k1 = (c1 == (uint32_t)i) || (c1 == (uint32_t)j);
            bool mvalid = (M0 != ~0ull);
            if (mvalid) {
                uint32_t c2 = (uint32_t)M0;
                if (c2 == (uint32_t)i || c2 == (uint32_t)j) mvalid = false;
            }
            if (!k1) {
                if (nk < K0) { rowkey[k] = nk; rowkey2[k] = K0; }
                else rowkey2[k] = mvalid ? ((nk < M0) ? nk : M0) : ~0ull;
            } else {
                if (mvalid) {
                    if (nk < M0) { rowkey[k] = nk; rowkey2[k] = M0; }
                    else { rowkey[k] = M0; rowkey2[k] = ~0ull; }
                } else {
                    int idx = atomicAdd(&nrecb[m & 1], 1); list_l[idx] = k;
                }
            }
        }
        LBAR();                                            // bar3
        int ncr = nrecb[m & 1];

        // ---- Phase C: wave0 finalizes row i's top-2; waves 1..15 rescan list ----
        if (wave == 0) {
            ull a = (lane < 16) ? wpB1[lane] : ~0ull;
            ull bb = (lane < 16) ? wpB2[lane] : ~0ull;
            ull m1 = wmin64_16(a);
            ull bm = __ballot((a == m1) && (lane < 16));
            int lw = __ffsll((long long)bm) - 1;
            ull a2 = (lane == lw) ? bb : a;
            ull m2 = wmin64_16(a2);
            if (lane == 0) { rowkey[i] = m1; rowkey2[i] = m2; }
        } else {
            for (int z = wave - 1; z < ncr; z += 15) {
                int r = list_l[z];
                int tsr = ts_l[r];
                const float* Rr = Db + (size_t)r * TN;
                ull a = ~0ull, bsec = ~0ull;
                #pragma unroll
                for (int q = 0; q < 4; ++q) {
                    int s0 = (lane << 2) + (q << 8);
                    float4 v = *(const float4*)(Rr + s0);
                    int4 ts4 = *(const int4*)(&ts_l[s0]);
                    uint32_t bits = (aw[s0 >> 5] >> (s0 & 31)) & 0xFu;
                    #pragma unroll
                    for (int e = 0; e < 4; ++e) {
                        int s = s0 + e;
                        if (!((bits >> e) & 1u) || s == r) continue;
                        int tss = (&ts4.x)[e];
                        float val = (&v.x)[e];
                        int tm = (tss > tsr) ? tss : tsr;
                        if (tm > m16)
                            val = (tss > tsr) ? Jl[(tss & 15) * TN + r]
                                              : Jl[(tsr & 15) * TN + s];
                        ull key = ((ull)f2sort(val) << 32) | (uint32_t)s;
                        if (key < a) { bsec = a; a = key; }
                        else if (key < bsec) { bsec = key; }
                    }
                }
                ull m1 = wmin64_all(a);
                ull bm = __ballot(a == m1);
                int lw = __ffsll((long long)bm) - 1;
                ull a2 = (lane == lw) ? bsec : a;
                ull m2 = wmin64_all(a2);
                if (lane == 0) { rowkey[r] = m1; rowkey2[r] = m2; }
            }
        }

        // ---- bar4: light barrier; every FWIN-th iter full fence + race fix-up ----
        if (mw == FWIN - 1) {
            FBAR();
            if (k < FWIN * FWIN) {
                int t1 = k / FWIN, t2 = k % FWIN;
                if (t1 != t2) {
                    int a = wtarg[t1], c = wtarg[t2];
                    if (a != c) {
                        bool lastA = true, lastC = true;
                        #pragma unroll
                        for (int t = 0; t < FWIN; ++t) {
                            if (t > t1 && wtarg[t] == a) lastA = false;
                            if (t > t2 && wtarg[t] == c) lastC = false;
                        }
                        if (lastA && lastC) {
                            int later = (t1 > t2) ? t1 : t2;
                            int earlier_i = (t1 > t2) ? c : a;
                            int iterlater = (m - (FWIN - 1)) + later;
                            float v = Jl[(iterlater & 15) * TN + earlier_i];
                            Db[(size_t)a * TN + c] = v;
                        }
                    }
                }
            }
            FBAR();
        } else {
            LBAR();
        }
    }

    // ---- epilogue: labels = rank of cluster root among active reps ----
    __syncthreads();
    int a = (aw[k >> 5] >> (k & 31)) & 1;
    ull mask = __ballot(a);
    int lanepre = __popcll(mask & (((ull)1 << lane) - 1ull));
    if (lane == 0) prefix_w[wave] = __popcll(mask);
    __syncthreads();
    if (k == 0) {
        int run = 0;
        for (int w2 = 0; w2 < 16; ++w2) { woff[w2] = run; run += prefix_w[w2]; }
    }
    __syncthreads();
    list_l[k] = woff[wave] + lanepre;
    __syncthreads();
    int p = k;
    while (!((aw[p >> 5] >> (p & 31)) & 1u)) p = parent_l[p];
    out_labels[(size_t)b * TN + k] = (float)list_l[p];
}

extern "C" void kernel_launch(void* const* d_in, const int* in_sizes, int n_in,
                              void* d_out, int out_size, void* d_ws, size_t ws_size,
                              hipStream_t stream) {
    const float* x = (const float*)d_in[0];
    float* out = (float*)d_out;

    float* xn      = (float*)d_ws;                          // NB*TN*CD floats
    float* Dwork   = xn + (size_t)NB * TN * CD;             // NB*TN*TN floats
    ull*   rowkey  = (ull*)(Dwork + (size_t)NB * TN * TN);  // NB*TN u64
    ull*   rowkey2 = rowkey + (size_t)NB * TN;              // NB*TN u64

    float* dist_out   = out;
    float* labels_out = out + (size_t)NB * TN * TN;

    norm_kernel<<<NB * TN, 256, 0, stream>>>(x, xn);
    dim3 g2(16, 16, NB);
    dist_kernel<<<g2, 256, 0, stream>>>(xn, dist_out, Dwork);
    rowmin_init_kernel<<<NB * TN, 256, 0, stream>>>(Dwork, rowkey, rowkey2);
    cluster_kernel<<<NB, 1024, 0, stream>>>(Dwork, rowkey, rowkey2, labels_out);
}

// Round 11
// 2598.424 us; speedup vs baseline: 1.9761x; 1.2619x over previous
//
#include <hip/hip_runtime.h>
#include <stdint.h>

#define TN 1024
#define CD 192
#define NB 8
#define NCLUST 196
#define NMERGE (TN - NCLUST)          // 828 kept merges at the cut
#define PMX 128                        // max mutual pairs merged per round
#define HIMASK 0xFFFFFFFF00000000ull

typedef unsigned long long ull;

// Workgroup barrier WITHOUT global-memory drain (LDS made visible only).
#define LBAR() asm volatile("s_waitcnt lgkmcnt(0)\n\ts_barrier" ::: "memory")
// Full fence barrier: drains global stores too.
#define FBAR() asm volatile("s_waitcnt vmcnt(0) lgkmcnt(0)\n\ts_barrier" ::: "memory")

__device__ __forceinline__ uint32_t f2sort(float f) {
    uint32_t u = __float_as_uint(f);
    return u ^ ((u >> 31) ? 0xFFFFFFFFu : 0x80000000u);
}

template<int CTRL>
__device__ __forceinline__ ull dpp_min64(ull x) {
    int lo = (int)(uint32_t)x, hi = (int)(uint32_t)(x >> 32);
    int tlo = __builtin_amdgcn_update_dpp(lo, lo, CTRL, 0xF, 0xF, false);
    int thi = __builtin_amdgcn_update_dpp(hi, hi, CTRL, 0xF, 0xF, false);
    ull t = ((ull)(uint32_t)thi << 32) | (uint32_t)tlo;
    return (t < x) ? t : x;
}
__device__ __forceinline__ ull wmin64_all(ull x) {
    x = dpp_min64<0x111>(x); x = dpp_min64<0x112>(x);
    x = dpp_min64<0x114>(x); x = dpp_min64<0x118>(x);
    x = dpp_min64<0x142>(x); x = dpp_min64<0x143>(x);
    int lo = __builtin_amdgcn_readlane((int)(uint32_t)x, 63);
    int hi = __builtin_amdgcn_readlane((int)(uint32_t)(x >> 32), 63);
    return ((ull)(uint32_t)hi << 32) | (uint32_t)lo;
}

// ---------------- normalize rows: xn = x / ||x|| ----------------
__global__ void norm_kernel(const float* __restrict__ x, float* __restrict__ xn) {
    int row = blockIdx.x;
    int t = threadIdx.x;
    __shared__ float ssum[4];
    float v = 0.f;
    if (t < CD) v = x[(size_t)row * CD + t];
    float s = v * v;
    #pragma unroll
    for (int off = 32; off > 0; off >>= 1) s += __shfl_xor(s, off, 64);
    if ((t & 63) == 0) ssum[t >> 6] = s;
    __syncthreads();
    float tot = ssum[0] + ssum[1] + ssum[2] + ssum[3];
    float nrm = __fsqrt_rn(tot);
    if (t < CD) xn[(size_t)row * CD + t] = __fdiv_rn(v, nrm);
}

// ---------------- dist = 1 - xn @ xn^T, 64x64 tiles ----------------
#define KC 32
__global__ __launch_bounds__(256) void dist_kernel(const float* __restrict__ xn,
                                                   float* __restrict__ dout,
                                                   float* __restrict__ dwork) {
    int b = blockIdx.z;
    int bm = blockIdx.y, bn = blockIdx.x;
    const float* X = xn + (size_t)b * TN * CD;
    __shared__ float As[KC][68];
    __shared__ float Bs[KC][68];
    int tid = threadIdx.x;
    int tx = tid & 15, ty = tid >> 4;
    int lr = tid >> 2;
    int lq = tid & 3;
    float acc[4][4];
    #pragma unroll
    for (int r = 0; r < 4; ++r)
        #pragma unroll
        for (int c = 0; c < 4; ++c) acc[r][c] = 0.f;

    for (int kc = 0; kc < CD; kc += KC) {
        float4 a0 = *(const float4*)&X[(size_t)(bm * 64 + lr) * CD + kc + lq * 4];
        float4 a1 = *(const float4*)&X[(size_t)(bm * 64 + lr) * CD + kc + (lq + 4) * 4];
        float4 b0 = *(const float4*)&X[(size_t)(bn * 64 + lr) * CD + kc + lq * 4];
        float4 b1 = *(const float4*)&X[(size_t)(bn * 64 + lr) * CD + kc + (lq + 4) * 4];
        __syncthreads();
        As[lq * 4 + 0][lr] = a0.x; As[lq * 4 + 1][lr] = a0.y;
        As[lq * 4 + 2][lr] = a0.z; As[lq * 4 + 3][lr] = a0.w;
        As[lq * 4 + 16][lr] = a1.x; As[lq * 4 + 17][lr] = a1.y;
        As[lq * 4 + 18][lr] = a1.z; As[lq * 4 + 19][lr] = a1.w;
        Bs[lq * 4 + 0][lr] = b0.x; Bs[lq * 4 + 1][lr] = b0.y;
        Bs[lq * 4 + 2][lr] = b0.z; Bs[lq * 4 + 3][lr] = b0.w;
        Bs[lq * 4 + 16][lr] = b1.x; Bs[lq * 4 + 17][lr] = b1.y;
        Bs[lq * 4 + 18][lr] = b1.z; Bs[lq * 4 + 19][lr] = b1.w;
        __syncthreads();
        #pragma unroll
        for (int kk = 0; kk < KC; ++kk) {
            float4 av = *(const float4*)&As[kk][ty * 4];
            float4 bv = *(const float4*)&Bs[kk][tx * 4];
            acc[0][0] += av.x * bv.x; acc[0][1] += av.x * bv.y;
            acc[0][2] += av.x * bv.z; acc[0][3] += av.x * bv.w;
            acc[1][0] += av.y * bv.x; acc[1][1] += av.y * bv.y;
            acc[1][2] += av.y * bv.z; acc[1][3] += av.y * bv.w;
            acc[2][0] += av.z * bv.x; acc[2][1] += av.z * bv.y;
            acc[2][2] += av.z * bv.z; acc[2][3] += av.z * bv.w;
            acc[3][0] += av.w * bv.x; acc[3][1] += av.w * bv.y;
            acc[3][2] += av.w * bv.z; acc[3][3] += av.w * bv.w;
        }
    }
    size_t obase = (size_t)b * TN * TN;
    #pragma unroll
    for (int r = 0; r < 4; ++r) {
        int mrow = bm * 64 + ty * 4 + r;
        float4 o;
        o.x = 1.0f - acc[r][0]; o.y = 1.0f - acc[r][1];
        o.z = 1.0f - acc[r][2]; o.w = 1.0f - acc[r][3];
        size_t idx = obase + (size_t)mrow * TN + bn * 64 + tx * 4;
        *(float4*)&dout[idx] = o;
        *(float4*)&dwork[idx] = o;
    }
}

// ---------------- parallel mutual-NN agglomeration (full dendrogram + cut) ----------------
// Per round: fresh NN for all alive rows; merge up to PMX mutual-NN pairs (valid for
// reducible average linkage - same dendrogram as greedy); two-level Lance-Williams for
// cross-pair entries; record merge heights. After 1023 merges: keep the 828 smallest-
// height merges (monotone greedy <=> height cut), union-find via pointer jumping,
// labels = rank of root (root = min member = reference's representative).
__global__ __launch_bounds__(1024) void cluster_kernel(float* __restrict__ D,
                                                       float* __restrict__ Tg,
                                                       float* __restrict__ Fg,
                                                       float* __restrict__ out_labels) {
    int b = blockIdx.x;
    float* Db = D + (size_t)b * TN * TN;
    float* Tb = Tg + (size_t)b * PMX * TN;
    float* Fb = Fg + (size_t)b * PMX * PMX;
    int k = threadIdx.x;
    int lane = k & 63, wave = k >> 6;

    __shared__ ull rowkey[TN];            // (f2sort(val)<<32)|col ; ~0 = dead
    __shared__ float sizes_l[TN];
    __shared__ uint32_t aw[TN / 32];
    __shared__ int pi_l[512], pj_l[512];
    __shared__ ull pkey_l[512];
    __shared__ int spi[PMX], spj[PMX];
    __shared__ ull skey[PMX];
    __shared__ ull mkey[TN];              // 1023 merge records: (val<<32)|i
    __shared__ int mij[TN];               // (i<<16)|j
    __shared__ int npair, nmerged, Pcur;
    __shared__ ull wpA[16];
    __shared__ int parent_l[TN];
    __shared__ uint32_t rw[32];
    __shared__ int woff[32];

    sizes_l[k] = 1.0f;
    rowkey[k] = ~0ull;
    if (k < 32) aw[k] = 0xFFFFFFFFu;
    if (k == 0) nmerged = 0;
    __syncthreads();

    for (int round = 0; round < 1200; ++round) {
        if (nmerged >= TN - 1) break;

        // ---- P1: NN recompute for all alive rows (fresh, from global D) ----
        for (int r = wave; r < TN; r += 16) {
            if (!((aw[r >> 5] >> (r & 31)) & 1u)) continue;
            const float* Rr = Db + (size_t)r * TN;
            ull a1 = ~0ull;
            #pragma unroll
            for (int q = 0; q < 4; ++q) {
                int s0 = (lane << 2) + (q << 8);
                float4 v = *(const float4*)(Rr + s0);
                uint32_t bits = (aw[s0 >> 5] >> (s0 & 31)) & 0xFu;
                #pragma unroll
                for (int e = 0; e < 4; ++e) {
                    int s = s0 + e;
                    if (((bits >> e) & 1u) && s != r) {
                        ull key = ((ull)f2sort((&v.x)[e]) << 32) | (uint32_t)s;
                        if (key < a1) a1 = key;
                    }
                }
            }
            a1 = wmin64_all(a1);
            if (lane == 0) rowkey[r] = a1;
        }
        if (k == 0) npair = 0;
        LBAR();

        // ---- P2: mutual-pair detection + global-min partials (fallback) ----
        {
            ull K = rowkey[k];
            ull cand = (K != ~0ull) ? ((K & HIMASK) | (uint32_t)k) : ~0ull;
            ull wm = wmin64_all(cand);
            if (lane == 0) wpA[wave] = wm;
            if (K != ~0ull) {
                int c = (int)(uint32_t)K;
                ull Kc = rowkey[c];
                if ((int)(uint32_t)Kc == k && k < c) {
                    int idx = atomicAdd(&npair, 1);
                    pi_l[idx] = k; pj_l[idx] = c;
                    pkey_l[idx] = (K & HIMASK) | (uint32_t)k;
                }
            }
        }
        LBAR();
        int np = npair;
        if (np == 0) {
            if (k == 0) {                      // FP-tie pathology: force global min pair
                ull g = wpA[0];
                for (int w = 1; w < 16; ++w) if (wpA[w] < g) g = wpA[w];
                int r = (int)(uint32_t)g;
                int c = (int)(uint32_t)rowkey[r];
                int i = r < c ? r : c, j = r < c ? c : r;
                spi[0] = i; spj[0] = j; skey[0] = (g & HIMASK) | (uint32_t)i;
                Pcur = 1;
            }
        } else {
            int P = np < PMX ? np : PMX;
            if (k == 0) Pcur = P;
            if (k < np) {                      // rank-select P smallest keys, sorted
                ull mykey = pkey_l[k];
                int rank = 0;
                for (int u = 0; u < np; ++u) {
                    ull o = pkey_l[u];
                    if (o < mykey || (o == mykey && u < k)) ++rank;
                }
                if (rank < P) { spi[rank] = pi_l[k]; spj[rank] = pj_l[k]; skey[rank] = mykey; }
            }
        }
        LBAR();
        int P = Pcur;

        // ---- P3: bulk LW rows -> T (old D); cross-pair two-level fixes -> F ----
        for (int q = wave; q < P; q += 16) {
            int i = spi[q], j = spj[q];
            float ni = sizes_l[i], nj = sizes_l[j];
            float ss = __fadd_rn(ni, nj);
            const float* Ri = Db + (size_t)i * TN;
            const float* Rj = Db + (size_t)j * TN;
            float* Tq = Tb + (size_t)q * TN;
            #pragma unroll
            for (int c4 = 0; c4 < 4; ++c4) {
                int s0 = (lane << 2) + (c4 << 8);
                float4 a = *(const float4*)(Ri + s0);
                float4 c = *(const float4*)(Rj + s0);
                float4 r;
                r.x = __fdiv_rn(__fadd_rn(__fmul_rn(ni, a.x), __fmul_rn(nj, c.x)), ss);
                r.y = __fdiv_rn(__fadd_rn(__fmul_rn(ni, a.y), __fmul_rn(nj, c.y)), ss);
                r.z = __fdiv_rn(__fadd_rn(__fmul_rn(ni, a.z), __fmul_rn(nj, c.z)), ss);
                r.w = __fdiv_rn(__fadd_rn(__fmul_rn(ni, a.w), __fmul_rn(nj, c.w)), ss);
                *(float4*)(Tq + s0) = r;
            }
        }
        for (int t = k; t < P * P; t += 1024) {
            int p = t / P, q = t - p * P;
            if (p < q) {                       // final d(P,Q) = LW_q over LW_p(old)
                int ip = spi[p], jp = spj[p], iq = spi[q], jq = spj[q];
                float nip = sizes_l[ip], njp = sizes_l[jp], sp = __fadd_rn(nip, njp);
                float niq = sizes_l[iq], njq = sizes_l[jq], sq = __fadd_rn(niq, njq);
                float t1 = __fdiv_rn(__fadd_rn(__fmul_rn(nip, Db[(size_t)ip * TN + iq]),
                                               __fmul_rn(njp, Db[(size_t)jp * TN + iq])), sp);
                float t2 = __fdiv_rn(__fadd_rn(__fmul_rn(nip, Db[(size_t)ip * TN + jq]),
                                               __fmul_rn(njp, Db[(size_t)jp * TN + jq])), sp);
                Fb[t] = __fdiv_rn(__fadd_rn(__fmul_rn(niq, t1), __fmul_rn(njq, t2)), sq);
            }
        }
        FBAR();                                // T,F landed; all old-D reads consumed

        // ---- P4a: write merged rows (coalesced) + columns (scattered) ----
        for (int q = wave; q < P; q += 16) {
            int i = spi[q];
            const float* Tq = Tb + (size_t)q * TN;
            float* Ri = Db + (size_t)i * TN;
            #pragma unroll
            for (int c4 = 0; c4 < 4; ++c4) {
                int s0 = (lane << 2) + (c4 << 8);
                float4 r = *(const float4*)(Tq + s0);
                *(float4*)(Ri + s0) = r;
            }
            #pragma unroll
            for (int c = 0; c < 16; ++c) {
                int s = lane + (c << 6);
                Db[(size_t)s * TN + i] = Tq[s];
            }
        }
        FBAR();
        // ---- P4b: overwrite cross-pair entries with exact two-level values ----
        for (int t = k; t < P * P; t += 1024) {
            int p = t / P, q = t - p * P;
            if (p < q) {
                float v = Fb[t];
                int ip = spi[p], iq = spi[q];
                Db[(size_t)ip * TN + iq] = v;
                Db[(size_t)iq * TN + ip] = v;
            }
        }
        // ---- P5: bookkeeping + merge records ----
        if (k < P) {
            int i = spi[k], j = spj[k];
            sizes_l[i] = __fadd_rn(sizes_l[i], sizes_l[j]);
            atomicAnd(&aw[j >> 5], ~(1u << (j & 31)));
            rowkey[j] = ~0ull;
            mkey[nmerged + k] = skey[k];
            mij[nmerged + k] = (i << 16) | j;
        }
        FBAR();                                // fixes landed before next-round reads
        if (k == 0) nmerged += P;
        LBAR();
    }

    // ---- epilogue: cut at 828 smallest heights, union-find, rank labels ----
    __syncthreads();
    parent_l[k] = k;
    if (k < 32) rw[k] = 0;
    __syncthreads();
    if (k < TN - 1) {
        ull mykey = mkey[k];
        int rank = 0;
        for (int u = 0; u < TN - 1; ++u) {
            ull o = mkey[u];
            if (o < mykey || (o == mykey && u < k)) ++rank;
        }
        if (rank < NMERGE) {
            int ij = mij[k];
            parent_l[ij & 0xFFFF] = ij >> 16;
        }
    }
    __syncthreads();
    #pragma unroll
    for (int it = 0; it < 11; ++it) {          // pointer jumping (depth <= 828 < 2^11)
        int p1 = parent_l[k];
        int g = parent_l[p1];
        __syncthreads();
        parent_l[k] = g;
        __syncthreads();
    }
    if (parent_l[k] == k) atomicOr(&rw[k >> 5], 1u << (k & 31));
    __syncthreads();
    if (k == 0) {
        int run = 0;
        for (int w = 0; w < 32; ++w) { woff[w] = run; run += __popc(rw[w]); }
    }
    __syncthreads();
    int p = parent_l[k];
    int rank = woff[p >> 5] + __popc(rw[p >> 5] & ((1u << (p & 31)) - 1u));
    out_labels[(size_t)b * TN + k] = (float)rank;
}

extern "C" void kernel_launch(void* const* d_in, const int* in_sizes, int n_in,
                              void* d_out, int out_size, void* d_ws, size_t ws_size,
                              hipStream_t stream) {
    const float* x = (const float*)d_in[0];
    float* out = (float*)d_out;

    float* xn    = (float*)d_ws;                          // NB*TN*CD floats (6.29 MB)
    float* Dwork = xn + (size_t)NB * TN * CD;             // NB*TN*TN floats (33.6 MB)
    // T/F scratch reuses the xn region (xn is dead after dist_kernel):
    float* Tg = xn;                                       // NB*PMX*TN floats (4.19 MB)
    float* Fg = xn + (size_t)NB * PMX * TN;               // NB*PMX*PMX floats (0.52 MB)

    float* dist_out   = out;
    float* labels_out = out + (size_t)NB * TN * TN;

    norm_kernel<<<NB * TN, 256, 0, stream>>>(x, xn);
    dim3 g2(16, 16, NB);
    dist_kernel<<<g2, 256, 0, stream>>>(xn, dist_out, Dwork);
    cluster_kernel<<<NB, 1024, 0, stream>>>(Dwork, Tg, Fg, labels_out);
}